// Round 4
// baseline (6110.997 us; speedup 1.0000x reference)
//
#include <hip/hip_runtime.h>
#include <math.h>

#define Bsz 16384
#define Msz 512
#define Nsz 2048

typedef _Float16 half8 __attribute__((ext_vector_type(8)));
typedef _Float16 half4 __attribute__((ext_vector_type(4)));
typedef float floatx4 __attribute__((ext_vector_type(4)));

struct HL { _Float16 h, l; };
__device__ __forceinline__ HL split1(float x) {
    HL r;
    r.h = (_Float16)x;
    r.l = (_Float16)(x - (float)r.h);   // exact residual (two-term split)
    return r;
}

// iter-0 prologue: v = batch -> f16 hi/lo pair, t2[b] = sum(v^2) per row.
__global__ __launch_bounds__(256) void init_kernel(const float* __restrict__ batch,
        _Float16* __restrict__ vh, _Float16* __restrict__ vl,
        float* __restrict__ t2) {
    const int wave = threadIdx.x >> 6;
    const int lane = threadIdx.x & 63;
    const int b = (blockIdx.x << 2) + wave;
    const float* row = batch + (size_t)b * Msz + lane * 8;
    float4 a = *(const float4*)row;
    float4 c = *(const float4*)(row + 4);
    half8 h, l;
    HL s0;
    s0 = split1(a.x); h[0] = s0.h; l[0] = s0.l;
    s0 = split1(a.y); h[1] = s0.h; l[1] = s0.l;
    s0 = split1(a.z); h[2] = s0.h; l[2] = s0.l;
    s0 = split1(a.w); h[3] = s0.h; l[3] = s0.l;
    s0 = split1(c.x); h[4] = s0.h; l[4] = s0.l;
    s0 = split1(c.y); h[5] = s0.h; l[5] = s0.l;
    s0 = split1(c.z); h[6] = s0.h; l[6] = s0.l;
    s0 = split1(c.w); h[7] = s0.h; l[7] = s0.l;
    *(half8*)(vh + (size_t)b * Msz + lane * 8) = h;
    *(half8*)(vl + (size_t)b * Msz + lane * 8) = l;
    float s = a.x*a.x + a.y*a.y + a.z*a.z + a.w*a.w
            + c.x*c.x + c.y*c.y + c.z*c.z + c.w*c.w;
#pragma unroll
    for (int off = 32; off > 0; off >>= 1) s += __shfl_down(s, off);
    if (lane == 0) t2[b] = s;
}

// One-time: D [M][N] fp32 -> Dhi/Dlo [M][N] (k=n contig, gemm2 B)
//                        and Dthi/Dtlo [N][M] (k=m contig, gemm1 B)
__global__ __launch_bounds__(256) void convD_kernel(const float* __restrict__ D,
        _Float16* __restrict__ Dhi, _Float16* __restrict__ Dlo,
        _Float16* __restrict__ Dthi, _Float16* __restrict__ Dtlo) {
    __shared__ float T[64][65];
    const int t = threadIdx.x;
    const int tx = t & 15, ty = t >> 4;
    const int n0 = blockIdx.x << 6, m0 = blockIdx.y << 6;
#pragma unroll
    for (int q = 0; q < 4; ++q) {
        const int mr = (ty << 2) + q;
        const int nc = tx << 2;
        float4 d = *(const float4*)(D + (size_t)(m0 + mr) * Nsz + n0 + nc);
        half4 h, l;
        HL s0 = split1(d.x), s1 = split1(d.y), s2 = split1(d.z), s3 = split1(d.w);
        h[0] = s0.h; l[0] = s0.l; h[1] = s1.h; l[1] = s1.l;
        h[2] = s2.h; l[2] = s2.l; h[3] = s3.h; l[3] = s3.l;
        *(half4*)(Dhi + (size_t)(m0 + mr) * Nsz + n0 + nc) = h;
        *(half4*)(Dlo + (size_t)(m0 + mr) * Nsz + n0 + nc) = l;
        T[nc + 0][mr] = d.x; T[nc + 1][mr] = d.y;
        T[nc + 2][mr] = d.z; T[nc + 3][mr] = d.w;
    }
    __syncthreads();
#pragma unroll
    for (int q = 0; q < 4; ++q) {
        const int nr = (ty << 2) + q;
        const int mc = tx << 2;
        float4 d = make_float4(T[nr][mc], T[nr][mc + 1], T[nr][mc + 2], T[nr][mc + 3]);
        half4 h, l;
        HL s0 = split1(d.x), s1 = split1(d.y), s2 = split1(d.z), s3 = split1(d.w);
        h[0] = s0.h; l[0] = s0.l; h[1] = s1.h; l[1] = s1.l;
        h[2] = s2.h; l[2] = s2.l; h[3] = s3.h; l[3] = s3.l;
        *(half4*)(Dthi + (size_t)(n0 + nr) * Msz + m0 + mc) = h;
        *(half4*)(Dtlo + (size_t)(n0 + nr) * Msz + m0 + mc) = l;
    }
}

// gemm1: alpha[b,n] = relu((first?0:alpha) + beta*(v@D)[b,n] - t[b]), t = g/sqrt(M)*sqrt(t2[b])
// + atomic na2[b] += sum(alpha_new^2).  No LDS: direct fragment loads.
// A = v pair [B][512] k-contig; B = Dt pair [N][512] k-contig.
// Block: 128x128 (4 waves 2x2, wave-tile 64x64). Grid: 2048 linear, col-tile = bid&15.
__global__ __launch_bounds__(256, 2) void gemm1_kernel(
        const _Float16* __restrict__ Ah, const _Float16* __restrict__ Al,
        const _Float16* __restrict__ Bh, const _Float16* __restrict__ Bl,
        const float* __restrict__ t2,
        float* __restrict__ alpha,
        float* __restrict__ na2,
        const float* __restrict__ beta_p, const float* __restrict__ gamma_p,
        int first) {
    const int tid = threadIdx.x;
    const int wave = tid >> 6, lane = tid & 63;
    const int wy = wave >> 1, wx = wave & 1;
    const int lm = lane & 15, lq = lane >> 4;
    const int bid = blockIdx.x;
    const int b0 = (bid >> 4) << 7;     // consecutive bids share the row-tile (A reuse)
    const int n0 = (bid & 15) << 7;

    floatx4 acc[4][4] = {};

    const _Float16* ah = Ah + (size_t)(b0 + wy * 64 + lm) * Msz + lq * 8;
    const _Float16* al = Al + (size_t)(b0 + wy * 64 + lm) * Msz + lq * 8;
    const _Float16* bh = Bh + (size_t)(n0 + wx * 64 + lm) * Msz + lq * 8;
    const _Float16* bl = Bl + (size_t)(n0 + wx * 64 + lm) * Msz + lq * 8;

    for (int k0 = 0; k0 < Msz; k0 += 32) {
        half8 fah[4], fal[4], fbh[4], fbl[4];
#pragma unroll
        for (int i = 0; i < 4; ++i) {
            fah[i] = *(const half8*)(ah + i * 16 * Msz + k0);
            fal[i] = *(const half8*)(al + i * 16 * Msz + k0);
        }
#pragma unroll
        for (int j = 0; j < 4; ++j) {
            fbh[j] = *(const half8*)(bh + j * 16 * Msz + k0);
            fbl[j] = *(const half8*)(bl + j * 16 * Msz + k0);
        }
#pragma unroll
        for (int j = 0; j < 4; ++j)
#pragma unroll
            for (int i = 0; i < 4; ++i) {
                acc[i][j] = __builtin_amdgcn_mfma_f32_16x16x32_f16(fah[i], fbh[j], acc[i][j], 0, 0, 0);
                acc[i][j] = __builtin_amdgcn_mfma_f32_16x16x32_f16(fah[i], fbl[j], acc[i][j], 0, 0, 0);
                acc[i][j] = __builtin_amdgcn_mfma_f32_16x16x32_f16(fal[i], fbh[j], acc[i][j], 0, 0, 0);
            }
    }

    const float beta = beta_p[0];
    const float tc = gamma_p[0] * 0.044194173824159216f;   // gamma / sqrt(512)
#pragma unroll
    for (int i = 0; i < 4; ++i) {
#pragma unroll
        for (int r = 0; r < 4; ++r) {
            const int b = b0 + wy * 64 + i * 16 + lq * 4 + r;
            const float tb = tc * sqrtf(t2[b]);
            float* arow = alpha + (size_t)b * Nsz + n0 + wx * 64 + lm;
            float s = 0.f;
#pragma unroll
            for (int j = 0; j < 4; ++j) {
                float z = first ? 0.f : arow[j * 16];
                float val = fmaxf(fmaf(beta, acc[i][j][r], z) - tb, 0.f);
                arow[j * 16] = val;
                s = fmaf(val, val, s);
            }
            s += __shfl_down(s, 8, 16);
            s += __shfl_down(s, 4, 16);
            s += __shfl_down(s, 2, 16);
            s += __shfl_down(s, 1, 16);
            if (lm == 0) atomicAdd(&na2[b], s);
        }
    }
}

// gemm2: v_new[b,m] = y - beta*(alpha@D^T) + beta/512*sqrt(na2[b])*v_old; writes v pair (in place)
// + atomic t2[b] += sum(v_new^2).  A = alpha fp32 [B][2048] (split on the fly); B = D pair [M][2048].
// Block: 128 rows x 64 cols (4 waves 2x2, wave-tile 64x32). Grid: 1024 linear, col-tile = bid&7.
__global__ __launch_bounds__(256, 2) void gemm2_kernel(
        const float* __restrict__ A,
        const _Float16* __restrict__ Bh, const _Float16* __restrict__ Bl,
        const float* __restrict__ na2,
        const float* __restrict__ y,
        _Float16* __restrict__ vh, _Float16* __restrict__ vl,
        float* __restrict__ t2,
        const float* __restrict__ beta_p) {
    const int tid = threadIdx.x;
    const int wave = tid >> 6, lane = tid & 63;
    const int wy = wave >> 1, wx = wave & 1;
    const int lm = lane & 15, lq = lane >> 4;
    const int bid = blockIdx.x;
    const int b0 = (bid >> 3) << 7;     // consecutive bids share the row-tile (alpha reuse)
    const int m0 = (bid & 7) << 6;

    floatx4 acc[4][2] = {};

    const float*    ap = A  + (size_t)(b0 + wy * 64 + lm) * Nsz + lq * 8;
    const _Float16* bh = Bh + (size_t)(m0 + wx * 32 + lm) * Nsz + lq * 8;
    const _Float16* bl = Bl + (size_t)(m0 + wx * 32 + lm) * Nsz + lq * 8;

    for (int k0 = 0; k0 < Nsz; k0 += 32) {
        half8 fah[4], fal[4], fbh[2], fbl[2];
#pragma unroll
        for (int i = 0; i < 4; ++i) {
            float4 p0 = *(const float4*)(ap + (size_t)i * 16 * Nsz + k0);
            float4 p1 = *(const float4*)(ap + (size_t)i * 16 * Nsz + k0 + 4);
            HL s;
            s = split1(p0.x); fah[i][0] = s.h; fal[i][0] = s.l;
            s = split1(p0.y); fah[i][1] = s.h; fal[i][1] = s.l;
            s = split1(p0.z); fah[i][2] = s.h; fal[i][2] = s.l;
            s = split1(p0.w); fah[i][3] = s.h; fal[i][3] = s.l;
            s = split1(p1.x); fah[i][4] = s.h; fal[i][4] = s.l;
            s = split1(p1.y); fah[i][5] = s.h; fal[i][5] = s.l;
            s = split1(p1.z); fah[i][6] = s.h; fal[i][6] = s.l;
            s = split1(p1.w); fah[i][7] = s.h; fal[i][7] = s.l;
        }
#pragma unroll
        for (int j = 0; j < 2; ++j) {
            fbh[j] = *(const half8*)(bh + j * 16 * Nsz + k0);
            fbl[j] = *(const half8*)(bl + j * 16 * Nsz + k0);
        }
#pragma unroll
        for (int j = 0; j < 2; ++j)
#pragma unroll
            for (int i = 0; i < 4; ++i) {
                acc[i][j] = __builtin_amdgcn_mfma_f32_16x16x32_f16(fah[i], fbh[j], acc[i][j], 0, 0, 0);
                acc[i][j] = __builtin_amdgcn_mfma_f32_16x16x32_f16(fah[i], fbl[j], acc[i][j], 0, 0, 0);
                acc[i][j] = __builtin_amdgcn_mfma_f32_16x16x32_f16(fal[i], fbh[j], acc[i][j], 0, 0, 0);
            }
    }

    const float beta = beta_p[0];
#pragma unroll
    for (int i = 0; i < 4; ++i) {
#pragma unroll
        for (int r = 0; r < 4; ++r) {
            const int b = b0 + wy * 64 + i * 16 + lq * 4 + r;
            const float cb = beta * (1.0f / 512.0f) * sqrtf(na2[b]);
            const size_t base = (size_t)b * Msz + m0 + wx * 32 + lm;
            float s = 0.f;
#pragma unroll
            for (int j = 0; j < 2; ++j) {
                const size_t idx = base + j * 16;
                float vold = (float)vh[idx] + (float)vl[idx];
                float val = y[idx] - beta * acc[i][j][r] + cb * vold;
                HL sp = split1(val);
                vh[idx] = sp.h;
                vl[idx] = sp.l;
                s = fmaf(val, val, s);
            }
            s += __shfl_down(s, 8, 16);
            s += __shfl_down(s, 4, 16);
            s += __shfl_down(s, 2, 16);
            s += __shfl_down(s, 1, 16);
            if (lm == 0) atomicAdd(&t2[b], s);
        }
    }
}

extern "C" void kernel_launch(void* const* d_in, const int* in_sizes, int n_in,
                              void* d_out, int out_size, void* d_ws, size_t ws_size,
                              hipStream_t stream) {
    (void)in_sizes; (void)n_in; (void)out_size; (void)ws_size;
    const float* batch   = (const float*)d_in[0];   // [B, M]
    const float* D       = (const float*)d_in[1];   // [M, N]
    const float* gamma_p = (const float*)d_in[2];   // scalar
    const float* beta_p  = (const float*)d_in[3];   // scalar

    float* alpha = (float*)d_out;                   // [B, N] fp32 state, in place

    // workspace (~42 MB, same footprint as round 3)
    _Float16* vh   = (_Float16*)d_ws;               // [B*M]
    _Float16* vl   = vh + (size_t)Bsz * Msz;
    _Float16* Dhi  = vl + (size_t)Bsz * Msz;        // [M*N]
    _Float16* Dlo  = Dhi + (size_t)Msz * Nsz;
    _Float16* Dthi = Dlo + (size_t)Msz * Nsz;       // [N*M]
    _Float16* Dtlo = Dthi + (size_t)Msz * Nsz;
    float*    t2   = (float*)(Dtlo + (size_t)Msz * Nsz);   // [B] sum v^2
    float*    na2  = t2 + Bsz;                             // [B] sum alpha^2

    convD_kernel<<<dim3(Nsz / 64, Msz / 64), 256, 0, stream>>>(D, Dhi, Dlo, Dthi, Dtlo);
    init_kernel<<<Bsz / 4, 256, 0, stream>>>(batch, vh, vl, t2);

    for (int it = 0; it < 10; ++it) {
        hipMemsetAsync(na2, 0, Bsz * sizeof(float), stream);
        gemm1_kernel<<<128 * 16, 256, 0, stream>>>(vh, vl, Dthi, Dtlo, t2,
                                                   alpha, na2, beta_p, gamma_p,
                                                   it == 0 ? 1 : 0);
        if (it < 9) {   // last iteration's new_v is unused by the reference output
            hipMemsetAsync(t2, 0, Bsz * sizeof(float), stream);
            gemm2_kernel<<<128 * 8, 256, 0, stream>>>(alpha, Dhi, Dlo, na2,
                                                      batch, vh, vl, t2, beta_p);
        }
    }
}

// Round 5
// 3204.803 us; speedup vs baseline: 1.9068x; 1.9068x over previous
//
#include <hip/hip_runtime.h>
#include <math.h>

#define Bsz 16384
#define Msz 512
#define Nsz 2048

typedef _Float16 half8 __attribute__((ext_vector_type(8)));
typedef _Float16 half4 __attribute__((ext_vector_type(4)));
typedef _Float16 half2v __attribute__((ext_vector_type(2)));
typedef float floatx4 __attribute__((ext_vector_type(4)));
typedef unsigned int uint;

struct HL { _Float16 h, l; };
__device__ __forceinline__ HL split1(float x) {
    HL r;
    r.h = (_Float16)x;
    r.l = (_Float16)(x - (float)r.h);   // exact residual (two-term split)
    return r;
}
__device__ __forceinline__ uint packHL(float x) {
    HL s = split1(x);
    return (uint)__builtin_bit_cast(unsigned short, s.h)
         | ((uint)__builtin_bit_cast(unsigned short, s.l) << 16);
}
__device__ __forceinline__ float unpackHL(uint w) {
    half2v p = __builtin_bit_cast(half2v, w);
    return (float)p.x + (float)p.y;
}

// iter-0 prologue: v = batch -> f16 hi/lo planes, t2[b] = sum(v^2) per row.
__global__ __launch_bounds__(256) void init_kernel(const float* __restrict__ batch,
        _Float16* __restrict__ vh, _Float16* __restrict__ vl,
        float* __restrict__ t2) {
    const int wave = threadIdx.x >> 6;
    const int lane = threadIdx.x & 63;
    const int b = (blockIdx.x << 2) + wave;
    const float* row = batch + (size_t)b * Msz + lane * 8;
    float4 a = *(const float4*)row;
    float4 c = *(const float4*)(row + 4);
    half8 h, l;
    HL s0;
    s0 = split1(a.x); h[0] = s0.h; l[0] = s0.l;
    s0 = split1(a.y); h[1] = s0.h; l[1] = s0.l;
    s0 = split1(a.z); h[2] = s0.h; l[2] = s0.l;
    s0 = split1(a.w); h[3] = s0.h; l[3] = s0.l;
    s0 = split1(c.x); h[4] = s0.h; l[4] = s0.l;
    s0 = split1(c.y); h[5] = s0.h; l[5] = s0.l;
    s0 = split1(c.z); h[6] = s0.h; l[6] = s0.l;
    s0 = split1(c.w); h[7] = s0.h; l[7] = s0.l;
    *(half8*)(vh + (size_t)b * Msz + lane * 8) = h;
    *(half8*)(vl + (size_t)b * Msz + lane * 8) = l;
    float s = a.x*a.x + a.y*a.y + a.z*a.z + a.w*a.w
            + c.x*c.x + c.y*c.y + c.z*c.z + c.w*c.w;
#pragma unroll
    for (int off = 32; off > 0; off >>= 1) s += __shfl_down(s, off);
    if (lane == 0) t2[b] = s;
}

// One-time: D [M][N] fp32 -> Dhi/Dlo [M][N] (k=n contig, gemm2 B)
//                        and Dthi/Dtlo [N][M] (k=m contig, gemm1 B)
__global__ __launch_bounds__(256) void convD_kernel(const float* __restrict__ D,
        _Float16* __restrict__ Dhi, _Float16* __restrict__ Dlo,
        _Float16* __restrict__ Dthi, _Float16* __restrict__ Dtlo) {
    __shared__ float T[64][65];
    const int t = threadIdx.x;
    const int tx = t & 15, ty = t >> 4;
    const int n0 = blockIdx.x << 6, m0 = blockIdx.y << 6;
#pragma unroll
    for (int q = 0; q < 4; ++q) {
        const int mr = (ty << 2) + q;
        const int nc = tx << 2;
        float4 d = *(const float4*)(D + (size_t)(m0 + mr) * Nsz + n0 + nc);
        half4 h, l;
        HL s0 = split1(d.x), s1 = split1(d.y), s2 = split1(d.z), s3 = split1(d.w);
        h[0] = s0.h; l[0] = s0.l; h[1] = s1.h; l[1] = s1.l;
        h[2] = s2.h; l[2] = s2.l; h[3] = s3.h; l[3] = s3.l;
        *(half4*)(Dhi + (size_t)(m0 + mr) * Nsz + n0 + nc) = h;
        *(half4*)(Dlo + (size_t)(m0 + mr) * Nsz + n0 + nc) = l;
        T[nc + 0][mr] = d.x; T[nc + 1][mr] = d.y;
        T[nc + 2][mr] = d.z; T[nc + 3][mr] = d.w;
    }
    __syncthreads();
#pragma unroll
    for (int q = 0; q < 4; ++q) {
        const int nr = (ty << 2) + q;
        const int mc = tx << 2;
        float4 d = make_float4(T[nr][mc], T[nr][mc + 1], T[nr][mc + 2], T[nr][mc + 3]);
        half4 h, l;
        HL s0 = split1(d.x), s1 = split1(d.y), s2 = split1(d.z), s3 = split1(d.w);
        h[0] = s0.h; l[0] = s0.l; h[1] = s1.h; l[1] = s1.l;
        h[2] = s2.h; l[2] = s2.l; h[3] = s3.h; l[3] = s3.l;
        *(half4*)(Dthi + (size_t)(n0 + nr) * Msz + m0 + mc) = h;
        *(half4*)(Dtlo + (size_t)(n0 + nr) * Msz + m0 + mc) = l;
    }
}

// gemm1: z = (first?0:alpha) + beta*(v@D); alpha = relu(z - t[b]); fused na2 atomic.
// A = v f16 planes [B][512]; B = Dt planes [N][512]. Tile 128x128, 4 waves 2x2.
// alpha stored packed (h|l<<16) in d_out; final iter writes fp32 in the same slots.
__global__ __launch_bounds__(256, 4) void gemm1_kernel(
        const _Float16* __restrict__ Avh, const _Float16* __restrict__ Avl,
        const _Float16* __restrict__ Bh, const _Float16* __restrict__ Bl,
        const float* __restrict__ t2,
        uint* __restrict__ alphaP,
        float* __restrict__ na2,
        const float* __restrict__ beta_p, const float* __restrict__ gamma_p,
        int first, int last) {
    __shared__ _Float16 lds[4 * 128 * 40];   // 40960 B: Ah, Al, Bhs, Bls; pad 40 (2-way free)
    _Float16* Ah  = lds;
    _Float16* Al  = lds + 5120;
    _Float16* Bhs = lds + 10240;
    _Float16* Bls = lds + 15360;

    const int tid = threadIdx.x;
    const int wave = tid >> 6, lane = tid & 63;
    const int wy = wave >> 1, wx = wave & 1;
    const int lm = lane & 15, lq = lane >> 4;
    const int bid = blockIdx.x;
    const int b0 = (bid >> 4) << 7;     // consecutive bids share row-tile (v L2 reuse)
    const int n0 = (bid & 15) << 7;

    floatx4 acc[4][4] = {};

    const int srow = tid >> 1;          // 0..127
    const int skq  = (tid & 1) << 4;    // 0 or 16 halves

    const _Float16* avhP = Avh + (size_t)(b0 + srow) * Msz + skq;
    const _Float16* avlP = Avl + (size_t)(b0 + srow) * Msz + skq;
    const _Float16* bhP  = Bh  + (size_t)(n0 + srow) * Msz + skq;
    const _Float16* blP  = Bl  + (size_t)(n0 + srow) * Msz + skq;

    _Float16* AhW = Ah  + srow * 40 + skq;
    _Float16* AlW = Al  + srow * 40 + skq;
    _Float16* BhW = Bhs + srow * 40 + skq;
    _Float16* BlW = Bls + srow * 40 + skq;

    const int aOff = (wy * 64 + lm) * 40 + lq * 8;
    const int bOff = (wx * 64 + lm) * 40 + lq * 8;

    for (int k0 = 0; k0 < Msz; k0 += 32) {
        half8 gah0 = *(const half8*)(avhP + k0);
        half8 gah1 = *(const half8*)(avhP + k0 + 8);
        half8 gal0 = *(const half8*)(avlP + k0);
        half8 gal1 = *(const half8*)(avlP + k0 + 8);
        half8 gbh0 = *(const half8*)(bhP + k0);
        half8 gbh1 = *(const half8*)(bhP + k0 + 8);
        half8 gbl0 = *(const half8*)(blP + k0);
        half8 gbl1 = *(const half8*)(blP + k0 + 8);

        __syncthreads();
        *(half8*)AhW = gah0; *(half8*)(AhW + 8) = gah1;
        *(half8*)AlW = gal0; *(half8*)(AlW + 8) = gal1;
        *(half8*)BhW = gbh0; *(half8*)(BhW + 8) = gbh1;
        *(half8*)BlW = gbl0; *(half8*)(BlW + 8) = gbl1;
        __syncthreads();

        half8 fah[4], fal[4];
#pragma unroll
        for (int i = 0; i < 4; ++i) {
            fah[i] = *(const half8*)(Ah + aOff + i * 640);
            fal[i] = *(const half8*)(Al + aOff + i * 640);
        }
#pragma unroll
        for (int j = 0; j < 4; ++j) {
            half8 fbh = *(const half8*)(Bhs + bOff + j * 640);
            half8 fbl = *(const half8*)(Bls + bOff + j * 640);
#pragma unroll
            for (int i = 0; i < 4; ++i) {
                acc[i][j] = __builtin_amdgcn_mfma_f32_16x16x32_f16(fah[i], fbh, acc[i][j], 0, 0, 0);
                acc[i][j] = __builtin_amdgcn_mfma_f32_16x16x32_f16(fah[i], fbl, acc[i][j], 0, 0, 0);
                acc[i][j] = __builtin_amdgcn_mfma_f32_16x16x32_f16(fal[i], fbh, acc[i][j], 0, 0, 0);
            }
        }
    }

    const float beta = beta_p[0];
    const float tc = gamma_p[0] * 0.044194173824159216f;   // gamma / sqrt(512)
#pragma unroll
    for (int i = 0; i < 4; ++i) {
#pragma unroll
        for (int r = 0; r < 4; ++r) {
            const int b = b0 + wy * 64 + i * 16 + lq * 4 + r;
            const float tb = tc * sqrtf(t2[b]);
            uint* arow = alphaP + (size_t)b * Nsz + n0 + wx * 64 + lm;
            float s = 0.f;
#pragma unroll
            for (int j = 0; j < 4; ++j) {
                float z = first ? 0.f : unpackHL(arow[j * 16]);
                float val = fmaxf(fmaf(beta, acc[i][j][r], z) - tb, 0.f);
                if (last) ((float*)arow)[j * 16] = val;   // final fp32, same 4-B slot
                else      arow[j * 16] = packHL(val);
                s = fmaf(val, val, s);
            }
            s += __shfl_down(s, 8, 16);
            s += __shfl_down(s, 4, 16);
            s += __shfl_down(s, 2, 16);
            s += __shfl_down(s, 1, 16);
            if (lm == 0) atomicAdd(&na2[b], s);
        }
    }
}

// gemm2: v = y - beta*(alpha@D^T) + beta/512*sqrt(na2[b])*v_old; fused t2 atomic.
// A = packed alpha [B][2048]; B = D planes [M][2048]. Tile 128x64, 2 waves (64x64 each).
__global__ __launch_bounds__(128, 4) void gemm2_kernel(
        const uint* __restrict__ alphaP,
        const _Float16* __restrict__ Bh, const _Float16* __restrict__ Bl,
        const float* __restrict__ na2,
        const float* __restrict__ y,
        _Float16* __restrict__ vh, _Float16* __restrict__ vl,
        float* __restrict__ t2,
        const float* __restrict__ beta_p) {
    __shared__ _Float16 lds[2 * 128 * 40 + 2 * 64 * 40];   // 30720 B
    _Float16* Ah  = lds;
    _Float16* Al  = lds + 5120;
    _Float16* Bhs = lds + 10240;
    _Float16* Bls = lds + 12800;

    const int tid = threadIdx.x;
    const int wave = tid >> 6, lane = tid & 63;
    const int lm = lane & 15, lq = lane >> 4;
    const int bid = blockIdx.x;
    const int b0 = (bid >> 3) << 7;     // consecutive bids share row-tile (alpha L2 reuse)
    const int m0 = (bid & 7) << 6;

    floatx4 acc[4][4] = {};

    // A staging: 2 rows/thread (r0, r0+64), 16 packed words each
    const int r0  = tid >> 1;
    const int skq = (tid & 1) << 4;     // word/half offset 0 or 16
    const uint* ap0 = alphaP + (size_t)(b0 + r0) * Nsz + skq;
    const uint* ap1 = ap0 + (size_t)64 * Nsz;
    _Float16* AhW0 = Ah + r0 * 40 + skq;
    _Float16* AlW0 = Al + r0 * 40 + skq;
    _Float16* AhW1 = AhW0 + 64 * 40;
    _Float16* AlW1 = AlW0 + 64 * 40;

    // B staging: 1 row-half/thread: row tid>>1 (0..63), half8 pair
    const _Float16* bhP = Bh + (size_t)(m0 + r0) * Nsz + skq;
    const _Float16* blP = Bl + (size_t)(m0 + r0) * Nsz + skq;
    _Float16* BhW = Bhs + r0 * 40 + skq;
    _Float16* BlW = Bls + r0 * 40 + skq;

    const int aOff = (wave * 64 + lm) * 40 + lq * 8;
    const int bOff = lm * 40 + lq * 8;

    for (int k0 = 0; k0 < Nsz; k0 += 32) {
        uint4 a0 = *(const uint4*)(ap0 + k0);
        uint4 a1 = *(const uint4*)(ap0 + k0 + 4);
        uint4 a2 = *(const uint4*)(ap0 + k0 + 8);
        uint4 a3 = *(const uint4*)(ap0 + k0 + 12);
        uint4 c0 = *(const uint4*)(ap1 + k0);
        uint4 c1 = *(const uint4*)(ap1 + k0 + 4);
        uint4 c2 = *(const uint4*)(ap1 + k0 + 8);
        uint4 c3 = *(const uint4*)(ap1 + k0 + 12);
        half8 gbh0 = *(const half8*)(bhP + k0);
        half8 gbh1 = *(const half8*)(bhP + k0 + 8);
        half8 gbl0 = *(const half8*)(blP + k0);
        half8 gbl1 = *(const half8*)(blP + k0 + 8);

        // unpack: hi = low16s, lo = high16s (v_perm_b32, 1 op per 2 elems)
        uint4 h0a, h0b, l0a, l0b, h1a, h1b, l1a, l1b;
        h0a.x = __builtin_amdgcn_perm(a0.y, a0.x, 0x05040100u);
        h0a.y = __builtin_amdgcn_perm(a0.w, a0.z, 0x05040100u);
        h0a.z = __builtin_amdgcn_perm(a1.y, a1.x, 0x05040100u);
        h0a.w = __builtin_amdgcn_perm(a1.w, a1.z, 0x05040100u);
        h0b.x = __builtin_amdgcn_perm(a2.y, a2.x, 0x05040100u);
        h0b.y = __builtin_amdgcn_perm(a2.w, a2.z, 0x05040100u);
        h0b.z = __builtin_amdgcn_perm(a3.y, a3.x, 0x05040100u);
        h0b.w = __builtin_amdgcn_perm(a3.w, a3.z, 0x05040100u);
        l0a.x = __builtin_amdgcn_perm(a0.y, a0.x, 0x07060302u);
        l0a.y = __builtin_amdgcn_perm(a0.w, a0.z, 0x07060302u);
        l0a.z = __builtin_amdgcn_perm(a1.y, a1.x, 0x07060302u);
        l0a.w = __builtin_amdgcn_perm(a1.w, a1.z, 0x07060302u);
        l0b.x = __builtin_amdgcn_perm(a2.y, a2.x, 0x07060302u);
        l0b.y = __builtin_amdgcn_perm(a2.w, a2.z, 0x07060302u);
        l0b.z = __builtin_amdgcn_perm(a3.y, a3.x, 0x07060302u);
        l0b.w = __builtin_amdgcn_perm(a3.w, a3.z, 0x07060302u);
        h1a.x = __builtin_amdgcn_perm(c0.y, c0.x, 0x05040100u);
        h1a.y = __builtin_amdgcn_perm(c0.w, c0.z, 0x05040100u);
        h1a.z = __builtin_amdgcn_perm(c1.y, c1.x, 0x05040100u);
        h1a.w = __builtin_amdgcn_perm(c1.w, c1.z, 0x05040100u);
        h1b.x = __builtin_amdgcn_perm(c2.y, c2.x, 0x05040100u);
        h1b.y = __builtin_amdgcn_perm(c2.w, c2.z, 0x05040100u);
        h1b.z = __builtin_amdgcn_perm(c3.y, c3.x, 0x05040100u);
        h1b.w = __builtin_amdgcn_perm(c3.w, c3.z, 0x05040100u);
        l1a.x = __builtin_amdgcn_perm(c0.y, c0.x, 0x07060302u);
        l1a.y = __builtin_amdgcn_perm(c0.w, c0.z, 0x07060302u);
        l1a.z = __builtin_amdgcn_perm(c1.y, c1.x, 0x07060302u);
        l1a.w = __builtin_amdgcn_perm(c1.w, c1.z, 0x07060302u);
        l1b.x = __builtin_amdgcn_perm(c2.y, c2.x, 0x07060302u);
        l1b.y = __builtin_amdgcn_perm(c2.w, c2.z, 0x07060302u);
        l1b.z = __builtin_amdgcn_perm(c3.y, c3.x, 0x07060302u);
        l1b.w = __builtin_amdgcn_perm(c3.w, c3.z, 0x07060302u);

        __syncthreads();
        *(uint4*)AhW0 = h0a; *(uint4*)(AhW0 + 8) = h0b;
        *(uint4*)AlW0 = l0a; *(uint4*)(AlW0 + 8) = l0b;
        *(uint4*)AhW1 = h1a; *(uint4*)(AhW1 + 8) = h1b;
        *(uint4*)AlW1 = l1a; *(uint4*)(AlW1 + 8) = l1b;
        *(half8*)BhW = gbh0; *(half8*)(BhW + 8) = gbh1;
        *(half8*)BlW = gbl0; *(half8*)(BlW + 8) = gbl1;
        __syncthreads();

        half8 fah[4], fal[4];
#pragma unroll
        for (int i = 0; i < 4; ++i) {
            fah[i] = *(const half8*)(Ah + aOff + i * 640);
            fal[i] = *(const half8*)(Al + aOff + i * 640);
        }
#pragma unroll
        for (int j = 0; j < 4; ++j) {
            half8 fbh = *(const half8*)(Bhs + bOff + j * 640);
            half8 fbl = *(const half8*)(Bls + bOff + j * 640);
#pragma unroll
            for (int i = 0; i < 4; ++i) {
                acc[i][j] = __builtin_amdgcn_mfma_f32_16x16x32_f16(fah[i], fbh, acc[i][j], 0, 0, 0);
                acc[i][j] = __builtin_amdgcn_mfma_f32_16x16x32_f16(fah[i], fbl, acc[i][j], 0, 0, 0);
                acc[i][j] = __builtin_amdgcn_mfma_f32_16x16x32_f16(fal[i], fbh, acc[i][j], 0, 0, 0);
            }
        }
    }

    const float beta = beta_p[0];
#pragma unroll
    for (int i = 0; i < 4; ++i) {
#pragma unroll
        for (int r = 0; r < 4; ++r) {
            const int b = b0 + wave * 64 + i * 16 + lq * 4 + r;
            const float cb = beta * (1.0f / 512.0f) * sqrtf(na2[b]);
            const size_t base = (size_t)b * Msz + m0 + lm;
            float s = 0.f;
#pragma unroll
            for (int j = 0; j < 4; ++j) {
                const size_t idx = base + j * 16;
                float vold = (float)vh[idx] + (float)vl[idx];
                float val = y[idx] - beta * acc[i][j][r] + cb * vold;
                HL sp = split1(val);
                vh[idx] = sp.h;
                vl[idx] = sp.l;
                s = fmaf(val, val, s);
            }
            s += __shfl_down(s, 8, 16);
            s += __shfl_down(s, 4, 16);
            s += __shfl_down(s, 2, 16);
            s += __shfl_down(s, 1, 16);
            if (lm == 0) atomicAdd(&t2[b], s);
        }
    }
}

extern "C" void kernel_launch(void* const* d_in, const int* in_sizes, int n_in,
                              void* d_out, int out_size, void* d_ws, size_t ws_size,
                              hipStream_t stream) {
    (void)in_sizes; (void)n_in; (void)out_size; (void)ws_size;
    const float* batch   = (const float*)d_in[0];   // [B, M]
    const float* D       = (const float*)d_in[1];   // [M, N]
    const float* gamma_p = (const float*)d_in[2];   // scalar
    const float* beta_p  = (const float*)d_in[3];   // scalar

    uint* alphaP = (uint*)d_out;    // packed hi/lo per element; fp32 after final iter

    // workspace (~42 MB)
    _Float16* vh   = (_Float16*)d_ws;               // [B*M]
    _Float16* vl   = vh + (size_t)Bsz * Msz;
    _Float16* Dhi  = vl + (size_t)Bsz * Msz;        // [M*N]
    _Float16* Dlo  = Dhi + (size_t)Msz * Nsz;
    _Float16* Dthi = Dlo + (size_t)Msz * Nsz;       // [N*M]
    _Float16* Dtlo = Dthi + (size_t)Msz * Nsz;
    float*    t2   = (float*)(Dtlo + (size_t)Msz * Nsz);   // [B] sum v^2
    float*    na2  = t2 + Bsz;                             // [B] sum alpha^2

    convD_kernel<<<dim3(Nsz / 64, Msz / 64), 256, 0, stream>>>(D, Dhi, Dlo, Dthi, Dtlo);
    init_kernel<<<Bsz / 4, 256, 0, stream>>>(batch, vh, vl, t2);

    for (int it = 0; it < 10; ++it) {
        hipMemsetAsync(na2, 0, Bsz * sizeof(float), stream);
        gemm1_kernel<<<128 * 16, 256, 0, stream>>>(vh, vl, Dthi, Dtlo, t2,
                                                   alphaP, na2, beta_p, gamma_p,
                                                   it == 0 ? 1 : 0, it == 9 ? 1 : 0);
        if (it < 9) {   // last iteration's new_v is unused by the reference output
            hipMemsetAsync(t2, 0, Bsz * sizeof(float), stream);
            gemm2_kernel<<<128 * 8, 128, 0, stream>>>(alphaP, Dhi, Dlo, na2,
                                                      batch, vh, vl, t2, beta_p);
        }
    }
}

// Round 6
// 3049.486 us; speedup vs baseline: 2.0039x; 1.0509x over previous
//
#include <hip/hip_runtime.h>
#include <math.h>

#define Bsz 16384
#define Msz 512
#define Nsz 2048

typedef _Float16 half8 __attribute__((ext_vector_type(8)));
typedef _Float16 half4 __attribute__((ext_vector_type(4)));
typedef _Float16 half2v __attribute__((ext_vector_type(2)));
typedef float floatx16 __attribute__((ext_vector_type(16)));
typedef unsigned int uint;

struct HL { _Float16 h, l; };
__device__ __forceinline__ HL split1(float x) {
    HL r;
    r.h = (_Float16)x;
    r.l = (_Float16)(x - (float)r.h);   // exact residual (two-term split)
    return r;
}
__device__ __forceinline__ uint packHL(float x) {
    HL s = split1(x);
    return (uint)__builtin_bit_cast(unsigned short, s.h)
         | ((uint)__builtin_bit_cast(unsigned short, s.l) << 16);
}
__device__ __forceinline__ float unpackHL(uint w) {
    half2v p = __builtin_bit_cast(half2v, w);
    return (float)p.x + (float)p.y;
}

// iter-0 prologue: v = batch -> f16 hi/lo planes, t2[b] = sum(v^2) per row.
__global__ __launch_bounds__(256) void init_kernel(const float* __restrict__ batch,
        _Float16* __restrict__ vh, _Float16* __restrict__ vl,
        float* __restrict__ t2) {
    const int wave = threadIdx.x >> 6;
    const int lane = threadIdx.x & 63;
    const int b = (blockIdx.x << 2) + wave;
    const float* row = batch + (size_t)b * Msz + lane * 8;
    float4 a = *(const float4*)row;
    float4 c = *(const float4*)(row + 4);
    half8 h, l;
    HL s0;
    s0 = split1(a.x); h[0] = s0.h; l[0] = s0.l;
    s0 = split1(a.y); h[1] = s0.h; l[1] = s0.l;
    s0 = split1(a.z); h[2] = s0.h; l[2] = s0.l;
    s0 = split1(a.w); h[3] = s0.h; l[3] = s0.l;
    s0 = split1(c.x); h[4] = s0.h; l[4] = s0.l;
    s0 = split1(c.y); h[5] = s0.h; l[5] = s0.l;
    s0 = split1(c.z); h[6] = s0.h; l[6] = s0.l;
    s0 = split1(c.w); h[7] = s0.h; l[7] = s0.l;
    *(half8*)(vh + (size_t)b * Msz + lane * 8) = h;
    *(half8*)(vl + (size_t)b * Msz + lane * 8) = l;
    float s = a.x*a.x + a.y*a.y + a.z*a.z + a.w*a.w
            + c.x*c.x + c.y*c.y + c.z*c.z + c.w*c.w;
#pragma unroll
    for (int off = 32; off > 0; off >>= 1) s += __shfl_down(s, off);
    if (lane == 0) t2[b] = s;
}

// One-time: D [M][N] fp32 -> Dhi/Dlo [M][N] (k=n contig, gemm2 B)
//                        and Dthi/Dtlo [N][M] (k=m contig, gemm1 B)
__global__ __launch_bounds__(256) void convD_kernel(const float* __restrict__ D,
        _Float16* __restrict__ Dhi, _Float16* __restrict__ Dlo,
        _Float16* __restrict__ Dthi, _Float16* __restrict__ Dtlo) {
    __shared__ float T[64][65];
    const int t = threadIdx.x;
    const int tx = t & 15, ty = t >> 4;
    const int n0 = blockIdx.x << 6, m0 = blockIdx.y << 6;
#pragma unroll
    for (int q = 0; q < 4; ++q) {
        const int mr = (ty << 2) + q;
        const int nc = tx << 2;
        float4 d = *(const float4*)(D + (size_t)(m0 + mr) * Nsz + n0 + nc);
        half4 h, l;
        HL s0 = split1(d.x), s1 = split1(d.y), s2 = split1(d.z), s3 = split1(d.w);
        h[0] = s0.h; l[0] = s0.l; h[1] = s1.h; l[1] = s1.l;
        h[2] = s2.h; l[2] = s2.l; h[3] = s3.h; l[3] = s3.l;
        *(half4*)(Dhi + (size_t)(m0 + mr) * Nsz + n0 + nc) = h;
        *(half4*)(Dlo + (size_t)(m0 + mr) * Nsz + n0 + nc) = l;
        T[nc + 0][mr] = d.x; T[nc + 1][mr] = d.y;
        T[nc + 2][mr] = d.z; T[nc + 3][mr] = d.w;
    }
    __syncthreads();
#pragma unroll
    for (int q = 0; q < 4; ++q) {
        const int nr = (ty << 2) + q;
        const int mc = tx << 2;
        float4 d = make_float4(T[nr][mc], T[nr][mc + 1], T[nr][mc + 2], T[nr][mc + 3]);
        half4 h, l;
        HL s0 = split1(d.x), s1 = split1(d.y), s2 = split1(d.z), s3 = split1(d.w);
        h[0] = s0.h; l[0] = s0.l; h[1] = s1.h; l[1] = s1.l;
        h[2] = s2.h; l[2] = s2.l; h[3] = s3.h; l[3] = s3.l;
        *(half4*)(Dthi + (size_t)(n0 + nr) * Msz + m0 + mc) = h;
        *(half4*)(Dtlo + (size_t)(n0 + nr) * Msz + m0 + mc) = l;
    }
}

// gemm1: z = (first?0:alpha) + beta*(v@D); alpha = relu(z - t[b]); fused na2 atomic.
// 128x128 tile, 4 waves 2x2, wave-tile 64x64 = 2x2 of 32x32x16 MFMAs.
// XCD swizzle: r = bid&127 (row-tile), j = bid>>7 (col-tile) -> row-tile sharers same XCD.
__global__ __launch_bounds__(256, 3) void gemm1_kernel(
        const _Float16* __restrict__ Avh, const _Float16* __restrict__ Avl,
        const _Float16* __restrict__ Bh, const _Float16* __restrict__ Bl,
        const float* __restrict__ t2,
        uint* __restrict__ alphaP,
        float* __restrict__ na2,
        const float* __restrict__ beta_p, const float* __restrict__ gamma_p,
        int first, int last) {
    __shared__ _Float16 lds[4 * 128 * 40];   // 40960 B, rows padded to 40 halves (80 B)
    _Float16* Ah  = lds;
    _Float16* Al  = lds + 5120;
    _Float16* Bhs = lds + 10240;
    _Float16* Bls = lds + 15360;

    const int tid = threadIdx.x;
    const int wave = tid >> 6, lane = tid & 63;
    const int wy = wave >> 1, wx = wave & 1;
    const int ln = lane & 31, lh = lane >> 5;
    const int bid = blockIdx.x;
    const int b0 = (bid & 127) << 7;
    const int n0 = (bid >> 7) << 7;

    floatx16 acc[2][2] = {};

    const int srow = tid >> 1;          // 0..127
    const int skq  = (tid & 1) << 4;    // 0 or 16 halves

    const _Float16* avhP = Avh + (size_t)(b0 + srow) * Msz + skq;
    const _Float16* avlP = Avl + (size_t)(b0 + srow) * Msz + skq;
    const _Float16* bhP  = Bh  + (size_t)(n0 + srow) * Msz + skq;
    const _Float16* blP  = Bl  + (size_t)(n0 + srow) * Msz + skq;

    _Float16* AhW = Ah  + srow * 40 + skq;
    _Float16* AlW = Al  + srow * 40 + skq;
    _Float16* BhW = Bhs + srow * 40 + skq;
    _Float16* BlW = Bls + srow * 40 + skq;

    const int aBase = (wy * 64 + ln) * 40 + lh * 8;   // + i*32*40 + ks*16
    const int bBase = (wx * 64 + ln) * 40 + lh * 8;

    for (int k0 = 0; k0 < Msz; k0 += 32) {
        half8 gah0 = *(const half8*)(avhP + k0);
        half8 gah1 = *(const half8*)(avhP + k0 + 8);
        half8 gal0 = *(const half8*)(avlP + k0);
        half8 gal1 = *(const half8*)(avlP + k0 + 8);
        half8 gbh0 = *(const half8*)(bhP + k0);
        half8 gbh1 = *(const half8*)(bhP + k0 + 8);
        half8 gbl0 = *(const half8*)(blP + k0);
        half8 gbl1 = *(const half8*)(blP + k0 + 8);

        __syncthreads();
        *(half8*)AhW = gah0; *(half8*)(AhW + 8) = gah1;
        *(half8*)AlW = gal0; *(half8*)(AlW + 8) = gal1;
        *(half8*)BhW = gbh0; *(half8*)(BhW + 8) = gbh1;
        *(half8*)BlW = gbl0; *(half8*)(BlW + 8) = gbl1;
        __syncthreads();

#pragma unroll
        for (int ks = 0; ks < 2; ++ks) {
            half8 fah[2], fal[2], fbh[2], fbl[2];
#pragma unroll
            for (int i = 0; i < 2; ++i) {
                fah[i] = *(const half8*)(Ah + aBase + i * 1280 + ks * 16);
                fal[i] = *(const half8*)(Al + aBase + i * 1280 + ks * 16);
                fbh[i] = *(const half8*)(Bhs + bBase + i * 1280 + ks * 16);
                fbl[i] = *(const half8*)(Bls + bBase + i * 1280 + ks * 16);
            }
#pragma unroll
            for (int j = 0; j < 2; ++j)
#pragma unroll
                for (int i = 0; i < 2; ++i) {
                    acc[i][j] = __builtin_amdgcn_mfma_f32_32x32x16_f16(fah[i], fbh[j], acc[i][j], 0, 0, 0);
                    acc[i][j] = __builtin_amdgcn_mfma_f32_32x32x16_f16(fah[i], fbl[j], acc[i][j], 0, 0, 0);
                    acc[i][j] = __builtin_amdgcn_mfma_f32_32x32x16_f16(fal[i], fbh[j], acc[i][j], 0, 0, 0);
                }
        }
    }

    const float beta = beta_p[0];
    const float tc = gamma_p[0] * 0.044194173824159216f;   // gamma / sqrt(512)
#pragma unroll
    for (int i = 0; i < 2; ++i) {
#pragma unroll
        for (int reg = 0; reg < 16; ++reg) {
            const int rr = (reg & 3) + 8 * (reg >> 2) + 4 * lh;   // 0..31
            const int b = b0 + wy * 64 + i * 32 + rr;
            const float tb = tc * sqrtf(t2[b]);
            uint* arow = alphaP + (size_t)b * Nsz + n0 + wx * 64 + ln;
            float s = 0.f;
#pragma unroll
            for (int j = 0; j < 2; ++j) {
                float z = first ? 0.f : unpackHL(arow[j * 32]);
                float val = fmaxf(fmaf(beta, acc[i][j][reg], z) - tb, 0.f);
                if (last) ((float*)arow)[j * 32] = val;   // final fp32, same 4-B slot
                else      arow[j * 32] = packHL(val);
                s = fmaf(val, val, s);
            }
            s += __shfl_down(s, 16, 32);
            s += __shfl_down(s, 8, 32);
            s += __shfl_down(s, 4, 32);
            s += __shfl_down(s, 2, 32);
            s += __shfl_down(s, 1, 32);
            if (ln == 0) atomicAdd(&na2[b], s);
        }
    }
}

// gemm2: v = y - beta*(alpha@D^T) + beta/512*sqrt(na2[b])*v_old; fused t2 atomic.
// 128x128 tile, 4 waves 2x2, 32x32x16 MFMAs. A = packed alpha (perm-unpacked).
// XCD swizzle: r = bid&127, j = bid>>7 (0..3).
__global__ __launch_bounds__(256, 3) void gemm2_kernel(
        const uint* __restrict__ alphaP,
        const _Float16* __restrict__ Bh, const _Float16* __restrict__ Bl,
        const float* __restrict__ na2,
        const float* __restrict__ y,
        _Float16* __restrict__ vh, _Float16* __restrict__ vl,
        float* __restrict__ t2,
        const float* __restrict__ beta_p) {
    __shared__ _Float16 lds[4 * 128 * 40];   // 40960 B
    _Float16* Ah  = lds;
    _Float16* Al  = lds + 5120;
    _Float16* Bhs = lds + 10240;
    _Float16* Bls = lds + 15360;

    const int tid = threadIdx.x;
    const int wave = tid >> 6, lane = tid & 63;
    const int wy = wave >> 1, wx = wave & 1;
    const int ln = lane & 31, lh = lane >> 5;
    const int bid = blockIdx.x;
    const int b0 = (bid & 127) << 7;
    const int m0 = (bid >> 7) << 7;

    floatx16 acc[2][2] = {};

    const int srow = tid >> 1;          // 0..127
    const int skq  = (tid & 1) << 4;    // 0 or 16 (words for A, halves for B)

    const uint*     apP = alphaP + (size_t)(b0 + srow) * Nsz + skq;
    const _Float16* bhP = Bh + (size_t)(m0 + srow) * Nsz + skq;
    const _Float16* blP = Bl + (size_t)(m0 + srow) * Nsz + skq;

    _Float16* AhW = Ah  + srow * 40 + skq;
    _Float16* AlW = Al  + srow * 40 + skq;
    _Float16* BhW = Bhs + srow * 40 + skq;
    _Float16* BlW = Bls + srow * 40 + skq;

    const int aBase = (wy * 64 + ln) * 40 + lh * 8;
    const int bBase = (wx * 64 + ln) * 40 + lh * 8;

    for (int k0 = 0; k0 < Nsz; k0 += 32) {
        uint4 a0 = *(const uint4*)(apP + k0);
        uint4 a1 = *(const uint4*)(apP + k0 + 4);
        uint4 a2 = *(const uint4*)(apP + k0 + 8);
        uint4 a3 = *(const uint4*)(apP + k0 + 12);
        half8 gbh0 = *(const half8*)(bhP + k0);
        half8 gbh1 = *(const half8*)(bhP + k0 + 8);
        half8 gbl0 = *(const half8*)(blP + k0);
        half8 gbl1 = *(const half8*)(blP + k0 + 8);

        // unpack packed (h|l<<16): hi = low16s, lo = high16s
        uint4 ha, hb, la, lb;
        ha.x = __builtin_amdgcn_perm(a0.y, a0.x, 0x05040100u);
        ha.y = __builtin_amdgcn_perm(a0.w, a0.z, 0x05040100u);
        ha.z = __builtin_amdgcn_perm(a1.y, a1.x, 0x05040100u);
        ha.w = __builtin_amdgcn_perm(a1.w, a1.z, 0x05040100u);
        hb.x = __builtin_amdgcn_perm(a2.y, a2.x, 0x05040100u);
        hb.y = __builtin_amdgcn_perm(a2.w, a2.z, 0x05040100u);
        hb.z = __builtin_amdgcn_perm(a3.y, a3.x, 0x05040100u);
        hb.w = __builtin_amdgcn_perm(a3.w, a3.z, 0x05040100u);
        la.x = __builtin_amdgcn_perm(a0.y, a0.x, 0x07060302u);
        la.y = __builtin_amdgcn_perm(a0.w, a0.z, 0x07060302u);
        la.z = __builtin_amdgcn_perm(a1.y, a1.x, 0x07060302u);
        la.w = __builtin_amdgcn_perm(a1.w, a1.z, 0x07060302u);
        lb.x = __builtin_amdgcn_perm(a2.y, a2.x, 0x07060302u);
        lb.y = __builtin_amdgcn_perm(a2.w, a2.z, 0x07060302u);
        lb.z = __builtin_amdgcn_perm(a3.y, a3.x, 0x07060302u);
        lb.w = __builtin_amdgcn_perm(a3.w, a3.z, 0x07060302u);

        __syncthreads();
        *(uint4*)AhW = ha; *(uint4*)(AhW + 8) = hb;
        *(uint4*)AlW = la; *(uint4*)(AlW + 8) = lb;
        *(half8*)BhW = gbh0; *(half8*)(BhW + 8) = gbh1;
        *(half8*)BlW = gbl0; *(half8*)(BlW + 8) = gbl1;
        __syncthreads();

#pragma unroll
        for (int ks = 0; ks < 2; ++ks) {
            half8 fah[2], fal[2], fbh[2], fbl[2];
#pragma unroll
            for (int i = 0; i < 2; ++i) {
                fah[i] = *(const half8*)(Ah + aBase + i * 1280 + ks * 16);
                fal[i] = *(const half8*)(Al + aBase + i * 1280 + ks * 16);
                fbh[i] = *(const half8*)(Bhs + bBase + i * 1280 + ks * 16);
                fbl[i] = *(const half8*)(Bls + bBase + i * 1280 + ks * 16);
            }
#pragma unroll
            for (int j = 0; j < 2; ++j)
#pragma unroll
                for (int i = 0; i < 2; ++i) {
                    acc[i][j] = __builtin_amdgcn_mfma_f32_32x32x16_f16(fah[i], fbh[j], acc[i][j], 0, 0, 0);
                    acc[i][j] = __builtin_amdgcn_mfma_f32_32x32x16_f16(fah[i], fbl[j], acc[i][j], 0, 0, 0);
                    acc[i][j] = __builtin_amdgcn_mfma_f32_32x32x16_f16(fal[i], fbh[j], acc[i][j], 0, 0, 0);
                }
        }
    }

    const float beta = beta_p[0];
#pragma unroll
    for (int i = 0; i < 2; ++i) {
#pragma unroll
        for (int reg = 0; reg < 16; ++reg) {
            const int rr = (reg & 3) + 8 * (reg >> 2) + 4 * lh;
            const int b = b0 + wy * 64 + i * 32 + rr;
            const float cb = beta * (1.0f / 512.0f) * sqrtf(na2[b]);
            const size_t base = (size_t)b * Msz + m0 + wx * 64 + ln;
            float s = 0.f;
#pragma unroll
            for (int j = 0; j < 2; ++j) {
                const size_t idx = base + j * 32;
                float vold = (float)vh[idx] + (float)vl[idx];
                float val = y[idx] - beta * acc[i][j][reg] + cb * vold;
                HL sp = split1(val);
                vh[idx] = sp.h;
                vl[idx] = sp.l;
                s = fmaf(val, val, s);
            }
            s += __shfl_down(s, 16, 32);
            s += __shfl_down(s, 8, 32);
            s += __shfl_down(s, 4, 32);
            s += __shfl_down(s, 2, 32);
            s += __shfl_down(s, 1, 32);
            if (ln == 0) atomicAdd(&t2[b], s);
        }
    }
}

extern "C" void kernel_launch(void* const* d_in, const int* in_sizes, int n_in,
                              void* d_out, int out_size, void* d_ws, size_t ws_size,
                              hipStream_t stream) {
    (void)in_sizes; (void)n_in; (void)out_size; (void)ws_size;
    const float* batch   = (const float*)d_in[0];   // [B, M]
    const float* D       = (const float*)d_in[1];   // [M, N]
    const float* gamma_p = (const float*)d_in[2];   // scalar
    const float* beta_p  = (const float*)d_in[3];   // scalar

    uint* alphaP = (uint*)d_out;    // packed hi/lo per element; fp32 after final iter

    // workspace (~42 MB)
    _Float16* vh   = (_Float16*)d_ws;               // [B*M]
    _Float16* vl   = vh + (size_t)Bsz * Msz;
    _Float16* Dhi  = vl + (size_t)Bsz * Msz;        // [M*N]
    _Float16* Dlo  = Dhi + (size_t)Msz * Nsz;
    _Float16* Dthi = Dlo + (size_t)Msz * Nsz;       // [N*M]
    _Float16* Dtlo = Dthi + (size_t)Msz * Nsz;
    float*    t2   = (float*)(Dtlo + (size_t)Msz * Nsz);   // [B] sum v^2
    float*    na2  = t2 + Bsz;                             // [B] sum alpha^2

    convD_kernel<<<dim3(Nsz / 64, Msz / 64), 256, 0, stream>>>(D, Dhi, Dlo, Dthi, Dtlo);
    init_kernel<<<Bsz / 4, 256, 0, stream>>>(batch, vh, vl, t2);

    for (int it = 0; it < 10; ++it) {
        hipMemsetAsync(na2, 0, Bsz * sizeof(float), stream);
        gemm1_kernel<<<2048, 256, 0, stream>>>(vh, vl, Dthi, Dtlo, t2,
                                               alphaP, na2, beta_p, gamma_p,
                                               it == 0 ? 1 : 0, it == 9 ? 1 : 0);
        if (it < 9) {   // last iteration's new_v is unused by the reference output
            hipMemsetAsync(t2, 0, Bsz * sizeof(float), stream);
            gemm2_kernel<<<512, 256, 0, stream>>>(alphaP, Dhi, Dlo, na2,
                                                  batch, vh, vl, t2, beta_p);
        }
    }
}

// Round 7
// 3015.931 us; speedup vs baseline: 2.0262x; 1.0111x over previous
//
#include <hip/hip_runtime.h>
#include <math.h>

#define Bsz 16384
#define Msz 512
#define Nsz 2048

typedef _Float16 half8 __attribute__((ext_vector_type(8)));
typedef _Float16 half4 __attribute__((ext_vector_type(4)));
typedef _Float16 half2v __attribute__((ext_vector_type(2)));
typedef float floatx16 __attribute__((ext_vector_type(16)));
typedef unsigned int uint;

struct HL { _Float16 h, l; };
__device__ __forceinline__ HL split1(float x) {
    HL r;
    r.h = (_Float16)x;
    r.l = (_Float16)(x - (float)r.h);   // exact residual (two-term split)
    return r;
}
__device__ __forceinline__ uint packHL(float x) {
    HL s = split1(x);
    return (uint)__builtin_bit_cast(unsigned short, s.h)
         | ((uint)__builtin_bit_cast(unsigned short, s.l) << 16);
}
__device__ __forceinline__ float unpackHL(uint w) {
    half2v p = __builtin_bit_cast(half2v, w);
    return (float)p.x + (float)p.y;
}

// fragment-permuted offset: element (r, k) of a [R][K] operand lives at
// ((r>>5)*(K/16) + (k>>4))*512 + (r&31)*16 + (k&15)
// -> one 32x32x16 MFMA fragment (32 rows x 16 k) = 1024 B contiguous.

// iter-0: v = batch -> permuted f16 hi/lo planes; t2[b] = sum(v^2).
__global__ __launch_bounds__(256) void init_kernel(const float* __restrict__ batch,
        _Float16* __restrict__ vh, _Float16* __restrict__ vl,
        float* __restrict__ t2) {
    const int wave = threadIdx.x >> 6;
    const int lane = threadIdx.x & 63;
    const int b = (blockIdx.x << 2) + wave;
    const float* row = batch + (size_t)b * Msz + lane * 8;
    float4 a = *(const float4*)row;
    float4 c = *(const float4*)(row + 4);
    half8 h, l;
    HL s0;
    s0 = split1(a.x); h[0] = s0.h; l[0] = s0.l;
    s0 = split1(a.y); h[1] = s0.h; l[1] = s0.l;
    s0 = split1(a.z); h[2] = s0.h; l[2] = s0.l;
    s0 = split1(a.w); h[3] = s0.h; l[3] = s0.l;
    s0 = split1(c.x); h[4] = s0.h; l[4] = s0.l;
    s0 = split1(c.y); h[5] = s0.h; l[5] = s0.l;
    s0 = split1(c.z); h[6] = s0.h; l[6] = s0.l;
    s0 = split1(c.w); h[7] = s0.h; l[7] = s0.l;
    // k = lane*8 .. lane*8+7 -> ktile = lane>>1, in-tile k-offset (lane&1)*8
    const size_t off = ((size_t)(b >> 5) * 32 + (lane >> 1)) * 512
                     + ((b & 31) << 4) + ((lane & 1) << 3);
    *(half8*)(vh + off) = h;
    *(half8*)(vl + off) = l;
    float s = a.x*a.x + a.y*a.y + a.z*a.z + a.w*a.w
            + c.x*c.x + c.y*c.y + c.z*c.z + c.w*c.w;
#pragma unroll
    for (int off2 = 32; off2 > 0; off2 >>= 1) s += __shfl_down(s, off2);
    if (lane == 0) t2[b] = s;
}

// One-time: D [M][N] fp32 -> Dperm hi/lo  (gemm2 B: r=m, k=n, K=2048)
//                        and Dtperm hi/lo (gemm1 B: r=n, k=m, K=512)
__global__ __launch_bounds__(256) void convD_kernel(const float* __restrict__ D,
        _Float16* __restrict__ Dph, _Float16* __restrict__ Dpl,
        _Float16* __restrict__ Dtph, _Float16* __restrict__ Dtpl) {
    __shared__ float T[64][65];
    const int t = threadIdx.x;
    const int tx = t & 15, ty = t >> 4;
    const int n0 = blockIdx.x << 6, m0 = blockIdx.y << 6;
#pragma unroll
    for (int q = 0; q < 4; ++q) {
        const int mr = m0 + (ty << 2) + q;
        const int nc = n0 + (tx << 2);
        float4 d = *(const float4*)(D + (size_t)mr * Nsz + nc);
        half4 h, l;
        HL s0 = split1(d.x), s1 = split1(d.y), s2 = split1(d.z), s3 = split1(d.w);
        h[0] = s0.h; l[0] = s0.l; h[1] = s1.h; l[1] = s1.l;
        h[2] = s2.h; l[2] = s2.l; h[3] = s3.h; l[3] = s3.l;
        const size_t o2 = ((size_t)(mr >> 5) * 128 + (nc >> 4)) * 512
                        + ((mr & 31) << 4) + (nc & 15);
        *(half4*)(Dph + o2) = h;
        *(half4*)(Dpl + o2) = l;
        T[(tx << 2) + 0][(ty << 2) + q] = d.x;
        T[(tx << 2) + 1][(ty << 2) + q] = d.y;
        T[(tx << 2) + 2][(ty << 2) + q] = d.z;
        T[(tx << 2) + 3][(ty << 2) + q] = d.w;
    }
    __syncthreads();
#pragma unroll
    for (int q = 0; q < 4; ++q) {
        const int nr = n0 + (ty << 2) + q;
        const int mc = m0 + (tx << 2);
        float4 d = make_float4(T[(ty << 2) + q][tx << 2],
                               T[(ty << 2) + q][(tx << 2) + 1],
                               T[(ty << 2) + q][(tx << 2) + 2],
                               T[(ty << 2) + q][(tx << 2) + 3]);
        half4 h, l;
        HL s0 = split1(d.x), s1 = split1(d.y), s2 = split1(d.z), s3 = split1(d.w);
        h[0] = s0.h; l[0] = s0.l; h[1] = s1.h; l[1] = s1.l;
        h[2] = s2.h; l[2] = s2.l; h[3] = s3.h; l[3] = s3.l;
        const size_t o1 = ((size_t)(nr >> 5) * 32 + (mc >> 4)) * 512
                        + ((nr & 31) << 4) + (mc & 15);
        *(half4*)(Dtph + o1) = h;
        *(half4*)(Dtpl + o1) = l;
    }
}

// gemm1: alpha = relu((first?0:alpha) + beta*(v@D) - t[b]); fused na2 atomic.
// ZERO LDS: A (v) and B (Dt) both fragment-permuted, direct coalesced loads,
// double-buffered in registers. 128x128 block, 4 waves 2x2, wave-tile 64x64.
__global__ __launch_bounds__(256, 3) void gemm1_kernel(
        const _Float16* __restrict__ Avh, const _Float16* __restrict__ Avl,
        const _Float16* __restrict__ Bh, const _Float16* __restrict__ Bl,
        const float* __restrict__ t2,
        uint* __restrict__ alphaP,
        float* __restrict__ na2,
        const float* __restrict__ beta_p, const float* __restrict__ gamma_p,
        int first, int last) {
    const int tid = threadIdx.x;
    const int wave = tid >> 6, lane = tid & 63;
    const int wy = wave >> 1, wx = wave & 1;
    const int ln = lane & 31, lh = lane >> 5;
    const int bid = blockIdx.x;
    const int b0 = (bid & 127) << 7;    // row-tile; sharers (stride-128 bids) land on same XCD
    const int n0 = (bid >> 7) << 7;

    floatx16 acc[2][2] = {};

    const int loff = ln * 16 + lh * 8;  // in-fragment lane offset (halves)
    const _Float16* ah = Avh + (size_t)((b0 + wy * 64) >> 5) * 32 * 512 + loff;
    const _Float16* al = Avl + (size_t)((b0 + wy * 64) >> 5) * 32 * 512 + loff;
    const _Float16* bh = Bh  + (size_t)((n0 + wx * 64) >> 5) * 32 * 512 + loff;
    const _Float16* bl = Bl  + (size_t)((n0 + wx * 64) >> 5) * 32 * 512 + loff;

    // frag buffer: [0..1]=A hi(i), [2..3]=A lo(i), [4..5]=B hi(j), [6..7]=B lo(j)
    half8 fr[2][8];
#define LOADFR(buf, kt)                                                        \
    {                                                                          \
        fr[buf][0] = *(const half8*)(ah + (kt) * 512);                         \
        fr[buf][1] = *(const half8*)(ah + 32 * 512 + (kt) * 512);              \
        fr[buf][2] = *(const half8*)(al + (kt) * 512);                         \
        fr[buf][3] = *(const half8*)(al + 32 * 512 + (kt) * 512);              \
        fr[buf][4] = *(const half8*)(bh + (kt) * 512);                         \
        fr[buf][5] = *(const half8*)(bh + 32 * 512 + (kt) * 512);              \
        fr[buf][6] = *(const half8*)(bl + (kt) * 512);                         \
        fr[buf][7] = *(const half8*)(bl + 32 * 512 + (kt) * 512);              \
    }
    LOADFR(0, 0)
#pragma unroll
    for (int kt = 0; kt < 32; ++kt) {
        const int cur = kt & 1;
        if (kt < 31) LOADFR(cur ^ 1, kt + 1)
#pragma unroll
        for (int j = 0; j < 2; ++j)
#pragma unroll
            for (int i = 0; i < 2; ++i) {
                acc[i][j] = __builtin_amdgcn_mfma_f32_32x32x16_f16(fr[cur][i],     fr[cur][4 + j], acc[i][j], 0, 0, 0);
                acc[i][j] = __builtin_amdgcn_mfma_f32_32x32x16_f16(fr[cur][i],     fr[cur][6 + j], acc[i][j], 0, 0, 0);
                acc[i][j] = __builtin_amdgcn_mfma_f32_32x32x16_f16(fr[cur][2 + i], fr[cur][4 + j], acc[i][j], 0, 0, 0);
            }
    }
#undef LOADFR

    const float beta = beta_p[0];
    const float tc = gamma_p[0] * 0.044194173824159216f;   // gamma / sqrt(512)
#pragma unroll
    for (int i = 0; i < 2; ++i) {
#pragma unroll
        for (int reg = 0; reg < 16; ++reg) {
            const int rr = (reg & 3) + 8 * (reg >> 2) + 4 * lh;   // 0..31
            const int b = b0 + wy * 64 + i * 32 + rr;
            const float tb = tc * sqrtf(t2[b]);
            uint* arow = alphaP + (size_t)b * Nsz + n0 + wx * 64 + ln;
            float s = 0.f;
#pragma unroll
            for (int j = 0; j < 2; ++j) {
                float z = first ? 0.f : unpackHL(arow[j * 32]);
                float val = fmaxf(fmaf(beta, acc[i][j][reg], z) - tb, 0.f);
                if (last) ((float*)arow)[j * 32] = val;   // final fp32, same 4-B slot
                else      arow[j * 32] = packHL(val);
                s = fmaf(val, val, s);
            }
            s += __shfl_down(s, 16, 32);
            s += __shfl_down(s, 8, 32);
            s += __shfl_down(s, 4, 32);
            s += __shfl_down(s, 2, 32);
            s += __shfl_down(s, 1, 32);
            if (ln == 0) atomicAdd(&na2[b], s);
        }
    }
}

// gemm2: v = y - beta*(alpha@D^T) + beta/512*sqrt(na2[b])*v_old; fused t2 atomic.
// A (packed alpha, plain layout) staged via LDS; B (D planes) fragment-permuted,
// direct from L2. 128x128 block, 4 waves 2x2. Epilogue writes v in permuted layout.
__global__ __launch_bounds__(256, 3) void gemm2_kernel(
        const uint* __restrict__ alphaP,
        const _Float16* __restrict__ Bh, const _Float16* __restrict__ Bl,
        const float* __restrict__ na2,
        const float* __restrict__ y,
        _Float16* __restrict__ vh, _Float16* __restrict__ vl,
        float* __restrict__ t2,
        const float* __restrict__ beta_p) {
    __shared__ _Float16 lds[2 * 128 * 40];   // 20480 B: A hi, A lo only
    _Float16* Ah = lds;
    _Float16* Al = lds + 5120;

    const int tid = threadIdx.x;
    const int wave = tid >> 6, lane = tid & 63;
    const int wy = wave >> 1, wx = wave & 1;
    const int ln = lane & 31, lh = lane >> 5;
    const int bid = blockIdx.x;
    const int b0 = (bid & 127) << 7;
    const int m0 = (bid >> 7) << 7;

    floatx16 acc[2][2] = {};

    const int srow = tid >> 1;          // 0..127
    const int skq  = (tid & 1) << 4;    // 0 or 16 words

    const uint* apP = alphaP + (size_t)(b0 + srow) * Nsz + skq;
    _Float16* AhW = Ah + srow * 40 + skq;
    _Float16* AlW = Al + srow * 40 + skq;

    const int loff = ln * 16 + lh * 8;
    const _Float16* bh = Bh + (size_t)((m0 + wx * 64) >> 5) * 128 * 512 + loff;
    const _Float16* bl = Bl + (size_t)((m0 + wx * 64) >> 5) * 128 * 512 + loff;

    const int aBase = (wy * 64 + ln) * 40 + lh * 8;

    for (int k0 = 0; k0 < Nsz; k0 += 32) {
        const int kt = k0 >> 4;
        // B fragments for this chunk, direct from permuted planes (L2-hot)
        half8 fbh[2][2], fbl[2][2];   // [ks][j]
#pragma unroll
        for (int ks = 0; ks < 2; ++ks)
#pragma unroll
            for (int j = 0; j < 2; ++j) {
                fbh[ks][j] = *(const half8*)(bh + (size_t)(j * 128 + kt + ks) * 512);
                fbl[ks][j] = *(const half8*)(bl + (size_t)(j * 128 + kt + ks) * 512);
            }

        uint4 a0 = *(const uint4*)(apP + k0);
        uint4 a1 = *(const uint4*)(apP + k0 + 4);
        uint4 a2 = *(const uint4*)(apP + k0 + 8);
        uint4 a3 = *(const uint4*)(apP + k0 + 12);

        uint4 ha, hb, la, lb;
        ha.x = __builtin_amdgcn_perm(a0.y, a0.x, 0x05040100u);
        ha.y = __builtin_amdgcn_perm(a0.w, a0.z, 0x05040100u);
        ha.z = __builtin_amdgcn_perm(a1.y, a1.x, 0x05040100u);
        ha.w = __builtin_amdgcn_perm(a1.w, a1.z, 0x05040100u);
        hb.x = __builtin_amdgcn_perm(a2.y, a2.x, 0x05040100u);
        hb.y = __builtin_amdgcn_perm(a2.w, a2.z, 0x05040100u);
        hb.z = __builtin_amdgcn_perm(a3.y, a3.x, 0x05040100u);
        hb.w = __builtin_amdgcn_perm(a3.w, a3.z, 0x05040100u);
        la.x = __builtin_amdgcn_perm(a0.y, a0.x, 0x07060302u);
        la.y = __builtin_amdgcn_perm(a0.w, a0.z, 0x07060302u);
        la.z = __builtin_amdgcn_perm(a1.y, a1.x, 0x07060302u);
        la.w = __builtin_amdgcn_perm(a1.w, a1.z, 0x07060302u);
        lb.x = __builtin_amdgcn_perm(a2.y, a2.x, 0x07060302u);
        lb.y = __builtin_amdgcn_perm(a2.w, a2.z, 0x07060302u);
        lb.z = __builtin_amdgcn_perm(a3.y, a3.x, 0x07060302u);
        lb.w = __builtin_amdgcn_perm(a3.w, a3.z, 0x07060302u);

        __syncthreads();
        *(uint4*)AhW = ha; *(uint4*)(AhW + 8) = hb;
        *(uint4*)AlW = la; *(uint4*)(AlW + 8) = lb;
        __syncthreads();

#pragma unroll
        for (int ks = 0; ks < 2; ++ks) {
            half8 fah[2], fal[2];
#pragma unroll
            for (int i = 0; i < 2; ++i) {
                fah[i] = *(const half8*)(Ah + aBase + i * 1280 + ks * 16);
                fal[i] = *(const half8*)(Al + aBase + i * 1280 + ks * 16);
            }
#pragma unroll
            for (int j = 0; j < 2; ++j)
#pragma unroll
                for (int i = 0; i < 2; ++i) {
                    acc[i][j] = __builtin_amdgcn_mfma_f32_32x32x16_f16(fah[i], fbh[ks][j], acc[i][j], 0, 0, 0);
                    acc[i][j] = __builtin_amdgcn_mfma_f32_32x32x16_f16(fah[i], fbl[ks][j], acc[i][j], 0, 0, 0);
                    acc[i][j] = __builtin_amdgcn_mfma_f32_32x32x16_f16(fal[i], fbh[ks][j], acc[i][j], 0, 0, 0);
                }
        }
    }

    const float beta = beta_p[0];
#pragma unroll
    for (int i = 0; i < 2; ++i) {
#pragma unroll
        for (int reg = 0; reg < 16; ++reg) {
            const int rr = (reg & 3) + 8 * (reg >> 2) + 4 * lh;
            const int b = b0 + wy * 64 + i * 32 + rr;
            const float cb = beta * (1.0f / 512.0f) * sqrtf(na2[b]);
            float s = 0.f;
#pragma unroll
            for (int j = 0; j < 2; ++j) {
                const int m = m0 + wx * 64 + j * 32 + ln;
                const size_t po = ((size_t)(b >> 5) * 32 + (m >> 4)) * 512
                                + ((b & 31) << 4) + (m & 15);
                const size_t yi = (size_t)b * Msz + m;
                float vold = (float)vh[po] + (float)vl[po];
                float val = y[yi] - beta * acc[i][j][reg] + cb * vold;
                HL sp = split1(val);
                vh[po] = sp.h;
                vl[po] = sp.l;
                s = fmaf(val, val, s);
            }
            s += __shfl_down(s, 16, 32);
            s += __shfl_down(s, 8, 32);
            s += __shfl_down(s, 4, 32);
            s += __shfl_down(s, 2, 32);
            s += __shfl_down(s, 1, 32);
            if (ln == 0) atomicAdd(&t2[b], s);
        }
    }
}

extern "C" void kernel_launch(void* const* d_in, const int* in_sizes, int n_in,
                              void* d_out, int out_size, void* d_ws, size_t ws_size,
                              hipStream_t stream) {
    (void)in_sizes; (void)n_in; (void)out_size; (void)ws_size;
    const float* batch   = (const float*)d_in[0];   // [B, M]
    const float* D       = (const float*)d_in[1];   // [M, N]
    const float* gamma_p = (const float*)d_in[2];   // scalar
    const float* beta_p  = (const float*)d_in[3];   // scalar

    uint* alphaP = (uint*)d_out;    // packed hi/lo per element (plain layout); fp32 after final iter

    // workspace (~50.5 MB; round 3 proved >= 50.3 MB available)
    _Float16* vh   = (_Float16*)d_ws;               // [B*M] permuted
    _Float16* vl   = vh + (size_t)Bsz * Msz;
    _Float16* Dph  = vl + (size_t)Bsz * Msz;        // [M*N] permuted (gemm2 B)
    _Float16* Dpl  = Dph + (size_t)Msz * Nsz;
    _Float16* Dtph = Dpl + (size_t)Msz * Nsz;       // [N*M] permuted (gemm1 B)
    _Float16* Dtpl = Dtph + (size_t)Msz * Nsz;
    float*    t2   = (float*)(Dtpl + (size_t)Msz * Nsz);   // [B] sum v^2
    float*    na2  = t2 + Bsz;                             // [B] sum alpha^2

    convD_kernel<<<dim3(Nsz / 64, Msz / 64), 256, 0, stream>>>(D, Dph, Dpl, Dtph, Dtpl);
    init_kernel<<<Bsz / 4, 256, 0, stream>>>(batch, vh, vl, t2);

    for (int it = 0; it < 10; ++it) {
        hipMemsetAsync(na2, 0, Bsz * sizeof(float), stream);
        gemm1_kernel<<<2048, 256, 0, stream>>>(vh, vl, Dtph, Dtpl, t2,
                                               alphaP, na2, beta_p, gamma_p,
                                               it == 0 ? 1 : 0, it == 9 ? 1 : 0);
        if (it < 9) {   // last iteration's new_v is unused by the reference output
            hipMemsetAsync(t2, 0, Bsz * sizeof(float), stream);
            gemm2_kernel<<<512, 256, 0, stream>>>(alphaP, Dph, Dpl, na2,
                                                  batch, vh, vl, t2, beta_p);
        }
    }
}

// Round 8
// 2851.346 us; speedup vs baseline: 2.1432x; 1.0577x over previous
//
#include <hip/hip_runtime.h>
#include <math.h>

#define Bsz 16384
#define Msz 512
#define Nsz 2048

typedef _Float16 half8 __attribute__((ext_vector_type(8)));
typedef _Float16 half4 __attribute__((ext_vector_type(4)));
typedef _Float16 half2v __attribute__((ext_vector_type(2)));
typedef float floatx16 __attribute__((ext_vector_type(16)));
typedef unsigned int uint;

struct HL { _Float16 h, l; };
__device__ __forceinline__ HL split1(float x) {
    HL r;
    r.h = (_Float16)x;
    r.l = (_Float16)(x - (float)r.h);   // exact residual (two-term split)
    return r;
}
__device__ __forceinline__ uint packHL(float x) {
    HL s = split1(x);
    return (uint)__builtin_bit_cast(unsigned short, s.h)
         | ((uint)__builtin_bit_cast(unsigned short, s.l) << 16);
}
__device__ __forceinline__ float unpackHL(uint w) {
    half2v p = __builtin_bit_cast(half2v, w);
    return (float)p.x + (float)p.y;
}

// async global->LDS, 16B per lane. LDS dest = wave-uniform base + lane*16.
__device__ __forceinline__ void gl_lds16(const _Float16* g, _Float16* l) {
    __builtin_amdgcn_global_load_lds(
        (const __attribute__((address_space(1))) unsigned int*)g,
        (__attribute__((address_space(3))) unsigned int*)l, 16, 0, 0);
}

// fragment-permuted layout (32x32x16 MFMA): element (r,k) of [R][K] at
// ((r>>5)*(K/16) + (k>>4))*512 + (r&31)*16 + (k&15)   [halves]
// -> one fragment (32 rows x 16 k) = 1024 B contiguous, verbatim-copyable.

// zero 19*Bsz floats (t2 slabs 1..9 + na2 slabs 0..9, contiguous)
__global__ __launch_bounds__(256) void zero_kernel(float4* __restrict__ p) {
    p[blockIdx.x * 256 + threadIdx.x] = make_float4(0.f, 0.f, 0.f, 0.f);
}

// iter-0: v = batch -> permuted f16 hi/lo planes; t2s[0][b] = sum(v^2).
__global__ __launch_bounds__(256) void init_kernel(const float* __restrict__ batch,
        _Float16* __restrict__ vh, _Float16* __restrict__ vl,
        float* __restrict__ t2) {
    const int wave = threadIdx.x >> 6;
    const int lane = threadIdx.x & 63;
    const int b = (blockIdx.x << 2) + wave;
    const float* row = batch + (size_t)b * Msz + lane * 8;
    float4 a = *(const float4*)row;
    float4 c = *(const float4*)(row + 4);
    half8 h, l;
    HL s0;
    s0 = split1(a.x); h[0] = s0.h; l[0] = s0.l;
    s0 = split1(a.y); h[1] = s0.h; l[1] = s0.l;
    s0 = split1(a.z); h[2] = s0.h; l[2] = s0.l;
    s0 = split1(a.w); h[3] = s0.h; l[3] = s0.l;
    s0 = split1(c.x); h[4] = s0.h; l[4] = s0.l;
    s0 = split1(c.y); h[5] = s0.h; l[5] = s0.l;
    s0 = split1(c.z); h[6] = s0.h; l[6] = s0.l;
    s0 = split1(c.w); h[7] = s0.h; l[7] = s0.l;
    const size_t off = ((size_t)(b >> 5) * 32 + (lane >> 1)) * 512
                     + ((b & 31) << 4) + ((lane & 1) << 3);
    *(half8*)(vh + off) = h;
    *(half8*)(vl + off) = l;
    float s = a.x*a.x + a.y*a.y + a.z*a.z + a.w*a.w
            + c.x*c.x + c.y*c.y + c.z*c.z + c.w*c.w;
#pragma unroll
    for (int off2 = 32; off2 > 0; off2 >>= 1) s += __shfl_down(s, off2);
    if (lane == 0) t2[b] = s;
}

// One-time: D [M][N] fp32 -> Dperm hi/lo  (gemm2 B: r=m, k=n, K=2048)
//                        and Dtperm hi/lo (gemm1 B: r=n, k=m, K=512)
__global__ __launch_bounds__(256) void convD_kernel(const float* __restrict__ D,
        _Float16* __restrict__ Dph, _Float16* __restrict__ Dpl,
        _Float16* __restrict__ Dtph, _Float16* __restrict__ Dtpl) {
    __shared__ float T[64][65];
    const int t = threadIdx.x;
    const int tx = t & 15, ty = t >> 4;
    const int n0 = blockIdx.x << 6, m0 = blockIdx.y << 6;
#pragma unroll
    for (int q = 0; q < 4; ++q) {
        const int mr = m0 + (ty << 2) + q;
        const int nc = n0 + (tx << 2);
        float4 d = *(const float4*)(D + (size_t)mr * Nsz + nc);
        half4 h, l;
        HL s0 = split1(d.x), s1 = split1(d.y), s2 = split1(d.z), s3 = split1(d.w);
        h[0] = s0.h; l[0] = s0.l; h[1] = s1.h; l[1] = s1.l;
        h[2] = s2.h; l[2] = s2.l; h[3] = s3.h; l[3] = s3.l;
        const size_t o2 = ((size_t)(mr >> 5) * 128 + (nc >> 4)) * 512
                        + ((mr & 31) << 4) + (nc & 15);
        *(half4*)(Dph + o2) = h;
        *(half4*)(Dpl + o2) = l;
        T[(tx << 2) + 0][(ty << 2) + q] = d.x;
        T[(tx << 2) + 1][(ty << 2) + q] = d.y;
        T[(tx << 2) + 2][(ty << 2) + q] = d.z;
        T[(tx << 2) + 3][(ty << 2) + q] = d.w;
    }
    __syncthreads();
#pragma unroll
    for (int q = 0; q < 4; ++q) {
        const int nr = n0 + (ty << 2) + q;
        const int mc = m0 + (tx << 2);
        float4 d = make_float4(T[(ty << 2) + q][tx << 2],
                               T[(ty << 2) + q][(tx << 2) + 1],
                               T[(ty << 2) + q][(tx << 2) + 2],
                               T[(ty << 2) + q][(tx << 2) + 3]);
        half4 h, l;
        HL s0 = split1(d.x), s1 = split1(d.y), s2 = split1(d.z), s3 = split1(d.w);
        h[0] = s0.h; l[0] = s0.l; h[1] = s1.h; l[1] = s1.l;
        h[2] = s2.h; l[2] = s2.l; h[3] = s3.h; l[3] = s3.l;
        const size_t o1 = ((size_t)(nr >> 5) * 32 + (mc >> 4)) * 512
                        + ((nr & 31) << 4) + (mc & 15);
        *(half4*)(Dtph + o1) = h;
        *(half4*)(Dtpl + o1) = l;
    }
}

// gemm1: alpha = relu((first?0:alpha) + beta*(v@D) - t[b]); fused na2 atomic.
// m97-style: both operands staged via global_load_lds (wave w stages plane w),
// 32KB single-buffer LDS, fragment-format (conflict-free b128 reads).
// 128x128 block, 4 waves 2x2, wave-tile 64x64, 32x32x16 MFMAs, K=512 (16 chunks).
__global__ __launch_bounds__(256, 3) void gemm1_kernel(
        const _Float16* __restrict__ Avh, const _Float16* __restrict__ Avl,
        const _Float16* __restrict__ Bth, const _Float16* __restrict__ Btl,
        const float* __restrict__ t2,
        uint* __restrict__ alphaP,
        float* __restrict__ na2,
        const float* __restrict__ beta_p, const float* __restrict__ gamma_p,
        int first, int last) {
    __shared__ _Float16 lds[16384];   // 32KB: Ah | Al | Bh | Bl, 4096 halves each

    const int tid = threadIdx.x;
    const int wave = tid >> 6, lane = tid & 63;
    const int wy = wave >> 1, wx = wave & 1;
    const int ln = lane & 31, lh = lane >> 5;
    const int bid = blockIdx.x;
    const int b0 = (bid & 127) << 7;    // row-tile sharers (stride-128 bids) -> same XCD
    const int n0 = (bid >> 7) << 7;
    const int R0 = b0 >> 5, C0 = n0 >> 5;

    floatx16 acc[2][2] = {};

    // staging source for this wave's plane (frag grid: [4 rtiles][32 ktiles])
    const _Float16* gsrc =
        (wave == 0) ? Avh + (size_t)R0 * 32 * 512 :
        (wave == 1) ? Avl + (size_t)R0 * 32 * 512 :
        (wave == 2) ? Bth + (size_t)C0 * 32 * 512 :
                      Btl + (size_t)C0 * 32 * 512;
    gsrc += lane * 8;                    // 16B per lane
    _Float16* lplane = lds + wave * 4096;

    const int ro = ln * 16 + lh * 8;     // in-fragment lane offset (halves)

    for (int c = 0; c < 16; ++c) {
        __syncthreads();                 // previous chunk's frag reads done
#pragma unroll
        for (int f = 0; f < 8; ++f) {    // frag (rtile i = f>>1, ktile j = f&1)
            const int i = f >> 1, j = f & 1;
            gl_lds16(gsrc + (((size_t)i * 32 + 2 * c + j) << 9), lplane + (f << 9));
        }
        __builtin_amdgcn_s_waitcnt(0);   // drain this wave's DMA
        __syncthreads();                 // all waves' planes staged

#pragma unroll
        for (int ks = 0; ks < 2; ++ks) {
            half8 fah[2], fal[2], fbh[2], fbl[2];
#pragma unroll
            for (int i = 0; i < 2; ++i) {
                const int sa = (((wy * 2 + i) << 1) + ks) << 9;
                const int sb = (((wx * 2 + i) << 1) + ks) << 9;
                fah[i] = *(const half8*)(lds + sa + ro);
                fal[i] = *(const half8*)(lds + 4096 + sa + ro);
                fbh[i] = *(const half8*)(lds + 8192 + sb + ro);
                fbl[i] = *(const half8*)(lds + 12288 + sb + ro);
            }
#pragma unroll
            for (int j = 0; j < 2; ++j)
#pragma unroll
                for (int i = 0; i < 2; ++i) {
                    acc[i][j] = __builtin_amdgcn_mfma_f32_32x32x16_f16(fah[i], fbh[j], acc[i][j], 0, 0, 0);
                    acc[i][j] = __builtin_amdgcn_mfma_f32_32x32x16_f16(fah[i], fbl[j], acc[i][j], 0, 0, 0);
                    acc[i][j] = __builtin_amdgcn_mfma_f32_32x32x16_f16(fal[i], fbh[j], acc[i][j], 0, 0, 0);
                }
        }
    }

    const float beta = beta_p[0];
    const float tc = gamma_p[0] * 0.044194173824159216f;   // gamma / sqrt(512)
#pragma unroll
    for (int i = 0; i < 2; ++i) {
#pragma unroll
        for (int reg = 0; reg < 16; ++reg) {
            const int rr = (reg & 3) + 8 * (reg >> 2) + 4 * lh;   // 0..31
            const int b = b0 + wy * 64 + i * 32 + rr;
            const float tb = tc * sqrtf(t2[b]);
            uint* arow = alphaP + (size_t)b * Nsz + n0 + wx * 64 + ln;
            float s = 0.f;
#pragma unroll
            for (int j = 0; j < 2; ++j) {
                float z = first ? 0.f : unpackHL(arow[j * 32]);
                float val = fmaxf(fmaf(beta, acc[i][j][reg], z) - tb, 0.f);
                if (last) ((float*)arow)[j * 32] = val;   // final fp32, same 4-B slot
                else      arow[j * 32] = packHL(val);
                s = fmaf(val, val, s);
            }
            s += __shfl_down(s, 16, 32);
            s += __shfl_down(s, 8, 32);
            s += __shfl_down(s, 4, 32);
            s += __shfl_down(s, 2, 32);
            s += __shfl_down(s, 1, 32);
            if (ln == 0) atomicAdd(&na2[b], s);
        }
    }
}

// gemm2: v = y - beta*(alpha@D^T) + beta/512*sqrt(na2[b])*v_old; fused t2 atomic.
// A (plain packed alpha) prefetched to VGPR, perm-unpacked, ds_write in fragment
// format; B (permuted D planes) via global_load_lds (waves 0/1). K=2048 (64 chunks).
__global__ __launch_bounds__(256, 3) void gemm2_kernel(
        const uint* __restrict__ alphaP,
        const _Float16* __restrict__ Bh, const _Float16* __restrict__ Bl,
        const float* __restrict__ na2,
        const float* __restrict__ y,
        _Float16* __restrict__ vh, _Float16* __restrict__ vl,
        float* __restrict__ t2,
        const float* __restrict__ beta_p) {
    __shared__ _Float16 lds[16384];   // Ah | Al | Bh | Bl, 4096 halves each

    const int tid = threadIdx.x;
    const int wave = tid >> 6, lane = tid & 63;
    const int wy = wave >> 1, wx = wave & 1;
    const int ln = lane & 31, lh = lane >> 5;
    const int bid = blockIdx.x;
    const int b0 = (bid & 127) << 7;
    const int m0 = (bid >> 7) << 7;
    const int C0 = m0 >> 5;

    floatx16 acc[2][2] = {};

    // A staging: thread (srow, skq) covers 16 k-words = one ktile of one row
    const int srow = tid >> 1;
    const int skq  = (tid & 1) << 4;
    const uint* apP = alphaP + (size_t)(b0 + srow) * Nsz + skq;
    _Float16* awh = lds + ((((srow >> 5) << 1) + (skq >> 4)) << 9) + ((srow & 31) << 4);
    _Float16* awl = awh + 4096;

    // B staging via gl_lds: wave0 -> Bh plane, wave1 -> Bl plane
    const _Float16* gB = ((wave & 1) ? Bl : Bh) + (size_t)C0 * 128 * 512 + lane * 8;
    _Float16* lB = lds + 8192 + (wave & 1) * 4096;

    const int ro = ln * 16 + lh * 8;

    uint4 a0 = *(const uint4*)(apP);
    uint4 a1 = *(const uint4*)(apP + 4);
    uint4 a2 = *(const uint4*)(apP + 8);
    uint4 a3 = *(const uint4*)(apP + 12);

    for (int c = 0; c < 64; ++c) {
        // unpack current A regs: hi = low16s, lo = high16s
        uint4 ha, hb, la, lb;
        ha.x = __builtin_amdgcn_perm(a0.y, a0.x, 0x05040100u);
        ha.y = __builtin_amdgcn_perm(a0.w, a0.z, 0x05040100u);
        ha.z = __builtin_amdgcn_perm(a1.y, a1.x, 0x05040100u);
        ha.w = __builtin_amdgcn_perm(a1.w, a1.z, 0x05040100u);
        hb.x = __builtin_amdgcn_perm(a2.y, a2.x, 0x05040100u);
        hb.y = __builtin_amdgcn_perm(a2.w, a2.z, 0x05040100u);
        hb.z = __builtin_amdgcn_perm(a3.y, a3.x, 0x05040100u);
        hb.w = __builtin_amdgcn_perm(a3.w, a3.z, 0x05040100u);
        la.x = __builtin_amdgcn_perm(a0.y, a0.x, 0x07060302u);
        la.y = __builtin_amdgcn_perm(a0.w, a0.z, 0x07060302u);
        la.z = __builtin_amdgcn_perm(a1.y, a1.x, 0x07060302u);
        la.w = __builtin_amdgcn_perm(a1.w, a1.z, 0x07060302u);
        lb.x = __builtin_amdgcn_perm(a2.y, a2.x, 0x07060302u);
        lb.y = __builtin_amdgcn_perm(a2.w, a2.z, 0x07060302u);
        lb.z = __builtin_amdgcn_perm(a3.y, a3.x, 0x07060302u);
        lb.w = __builtin_amdgcn_perm(a3.w, a3.z, 0x07060302u);

        // prefetch next chunk's A (completes during barrier+MFMA span)
        if (c < 63) {
            const uint* nx = apP + (c + 1) * 32;
            a0 = *(const uint4*)(nx);
            a1 = *(const uint4*)(nx + 4);
            a2 = *(const uint4*)(nx + 8);
            a3 = *(const uint4*)(nx + 12);
        }

        __syncthreads();                 // previous chunk's frag reads done
        if (wave < 2) {
#pragma unroll
            for (int f = 0; f < 8; ++f) {
                const int i = f >> 1, j = f & 1;
                gl_lds16(gB + (((size_t)i * 128 + 2 * c + j) << 9), lB + (f << 9));
            }
        }
        *(uint4*)awh = ha; *(uint4*)(awh + 8) = hb;
        *(uint4*)awl = la; *(uint4*)(awl + 8) = lb;
        __builtin_amdgcn_s_waitcnt(0);
        __syncthreads();

#pragma unroll
        for (int ks = 0; ks < 2; ++ks) {
            half8 fah[2], fal[2], fbh[2], fbl[2];
#pragma unroll
            for (int i = 0; i < 2; ++i) {
                const int sa = (((wy * 2 + i) << 1) + ks) << 9;
                const int sb = (((wx * 2 + i) << 1) + ks) << 9;
                fah[i] = *(const half8*)(lds + sa + ro);
                fal[i] = *(const half8*)(lds + 4096 + sa + ro);
                fbh[i] = *(const half8*)(lds + 8192 + sb + ro);
                fbl[i] = *(const half8*)(lds + 12288 + sb + ro);
            }
#pragma unroll
            for (int j = 0; j < 2; ++j)
#pragma unroll
                for (int i = 0; i < 2; ++i) {
                    acc[i][j] = __builtin_amdgcn_mfma_f32_32x32x16_f16(fah[i], fbh[j], acc[i][j], 0, 0, 0);
                    acc[i][j] = __builtin_amdgcn_mfma_f32_32x32x16_f16(fah[i], fbl[j], acc[i][j], 0, 0, 0);
                    acc[i][j] = __builtin_amdgcn_mfma_f32_32x32x16_f16(fal[i], fbh[j], acc[i][j], 0, 0, 0);
                }
        }
    }

    const float beta = beta_p[0];
#pragma unroll
    for (int i = 0; i < 2; ++i) {
#pragma unroll
        for (int reg = 0; reg < 16; ++reg) {
            const int rr = (reg & 3) + 8 * (reg >> 2) + 4 * lh;
            const int b = b0 + wy * 64 + i * 32 + rr;
            const float cb = beta * (1.0f / 512.0f) * sqrtf(na2[b]);
            float s = 0.f;
#pragma unroll
            for (int j = 0; j < 2; ++j) {
                const int m = m0 + wx * 64 + j * 32 + ln;
                const size_t po = ((size_t)(b >> 5) * 32 + (m >> 4)) * 512
                                + ((b & 31) << 4) + (m & 15);
                const size_t yi = (size_t)b * Msz + m;
                float vold = (float)vh[po] + (float)vl[po];
                float val = y[yi] - beta * acc[i][j][reg] + cb * vold;
                HL sp = split1(val);
                vh[po] = sp.h;
                vl[po] = sp.l;
                s = fmaf(val, val, s);
            }
            s += __shfl_down(s, 16, 32);
            s += __shfl_down(s, 8, 32);
            s += __shfl_down(s, 4, 32);
            s += __shfl_down(s, 2, 32);
            s += __shfl_down(s, 1, 32);
            if (ln == 0) atomicAdd(&t2[b], s);
        }
    }
}

extern "C" void kernel_launch(void* const* d_in, const int* in_sizes, int n_in,
                              void* d_out, int out_size, void* d_ws, size_t ws_size,
                              hipStream_t stream) {
    (void)in_sizes; (void)n_in; (void)out_size; (void)ws_size;
    const float* batch   = (const float*)d_in[0];   // [B, M]
    const float* D       = (const float*)d_in[1];   // [M, N]
    const float* gamma_p = (const float*)d_in[2];   // scalar
    const float* beta_p  = (const float*)d_in[3];   // scalar

    uint* alphaP = (uint*)d_out;    // packed hi/lo per element (plain layout); fp32 after final iter

    // workspace (~42.6 MB; round 3 proved >= 50.3 MB available)
    _Float16* vh   = (_Float16*)d_ws;               // [B*M] permuted
    _Float16* vl   = vh + (size_t)Bsz * Msz;
    _Float16* Dph  = vl + (size_t)Bsz * Msz;        // [M*N] permuted (gemm2 B)
    _Float16* Dpl  = Dph + (size_t)Msz * Nsz;
    _Float16* Dtph = Dpl + (size_t)Msz * Nsz;       // [N*M] permuted (gemm1 B)
    _Float16* Dtpl = Dtph + (size_t)Msz * Nsz;
    float*    t2s  = (float*)(Dtpl + (size_t)Msz * Nsz);   // [10][Bsz] sum v^2
    float*    na2s = t2s + 10 * Bsz;                        // [10][Bsz] sum alpha^2

    // zero t2 slabs 1..9 + na2 slabs 0..9 (contiguous 19*Bsz floats)
    zero_kernel<<<19 * Bsz / 1024, 256, 0, stream>>>((float4*)(t2s + Bsz));
    convD_kernel<<<dim3(Nsz / 64, Msz / 64), 256, 0, stream>>>(D, Dph, Dpl, Dtph, Dtpl);
    init_kernel<<<Bsz / 4, 256, 0, stream>>>(batch, vh, vl, t2s);   // writes t2 slab 0

    for (int it = 0; it < 10; ++it) {
        gemm1_kernel<<<2048, 256, 0, stream>>>(vh, vl, Dtph, Dtpl,
                                               t2s + (size_t)it * Bsz,
                                               alphaP,
                                               na2s + (size_t)it * Bsz,
                                               beta_p, gamma_p,
                                               it == 0 ? 1 : 0, it == 9 ? 1 : 0);
        if (it < 9) {   // last iteration's new_v is unused by the reference output
            gemm2_kernel<<<512, 256, 0, stream>>>(alphaP, Dph, Dpl,
                                                  na2s + (size_t)it * Bsz,
                                                  batch, vh, vl,
                                                  t2s + (size_t)(it + 1) * Bsz,
                                                  beta_p);
        }
    }
}

// Round 9
// 2343.308 us; speedup vs baseline: 2.6079x; 1.2168x over previous
//
#include <hip/hip_runtime.h>
#include <math.h>

#define Bsz 16384
#define Msz 512
#define Nsz 2048

typedef _Float16 half8 __attribute__((ext_vector_type(8)));
typedef _Float16 half4 __attribute__((ext_vector_type(4)));
typedef _Float16 half2v __attribute__((ext_vector_type(2)));
typedef float floatx16 __attribute__((ext_vector_type(16)));
typedef unsigned int uint;

struct HL { _Float16 h, l; };
__device__ __forceinline__ HL split1(float x) {
    HL r;
    r.h = (_Float16)x;
    r.l = (_Float16)(x - (float)r.h);   // exact residual (two-term split)
    return r;
}
__device__ __forceinline__ uint packHL(float x) {
    HL s = split1(x);
    return (uint)__builtin_bit_cast(unsigned short, s.h)
         | ((uint)__builtin_bit_cast(unsigned short, s.l) << 16);
}
__device__ __forceinline__ float unpackHL(uint w) {
    half2v p = __builtin_bit_cast(half2v, w);
    return (float)p.x + (float)p.y;
}

// async global->LDS, 16B per lane. LDS dest = wave-uniform base + lane*16.
__device__ __forceinline__ void gl_lds16(const _Float16* g, _Float16* l) {
    __builtin_amdgcn_global_load_lds(
        (const __attribute__((address_space(1))) unsigned int*)g,
        (__attribute__((address_space(3))) unsigned int*)l, 16, 0, 0);
}

// fragment-permuted layout (32x32x16 MFMA): element (r,k) of [R][K] at
// ((r>>5)*(K/16) + (k>>4))*512 + (r&31)*16 + (k&15)   [halves]

// zero 19*Bsz floats (t2 slabs 1..9 + na2 slabs 0..9, contiguous)
__global__ __launch_bounds__(256) void zero_kernel(float4* __restrict__ p) {
    p[blockIdx.x * 256 + threadIdx.x] = make_float4(0.f, 0.f, 0.f, 0.f);
}

// iter-0: v = batch -> single f16 permuted plane; t2s[0][b] = sum(v^2) (fp32).
__global__ __launch_bounds__(256) void init_kernel(const float* __restrict__ batch,
        _Float16* __restrict__ vh, float* __restrict__ t2) {
    const int wave = threadIdx.x >> 6;
    const int lane = threadIdx.x & 63;
    const int b = (blockIdx.x << 2) + wave;
    const float* row = batch + (size_t)b * Msz + lane * 8;
    float4 a = *(const float4*)row;
    float4 c = *(const float4*)(row + 4);
    half8 h;
    h[0] = (_Float16)a.x; h[1] = (_Float16)a.y;
    h[2] = (_Float16)a.z; h[3] = (_Float16)a.w;
    h[4] = (_Float16)c.x; h[5] = (_Float16)c.y;
    h[6] = (_Float16)c.z; h[7] = (_Float16)c.w;
    const size_t off = ((size_t)(b >> 5) * 32 + (lane >> 1)) * 512
                     + ((b & 31) << 4) + ((lane & 1) << 3);
    *(half8*)(vh + off) = h;
    float s = a.x*a.x + a.y*a.y + a.z*a.z + a.w*a.w
            + c.x*c.x + c.y*c.y + c.z*c.z + c.w*c.w;
#pragma unroll
    for (int off2 = 32; off2 > 0; off2 >>= 1) s += __shfl_down(s, off2);
    if (lane == 0) t2[b] = s;
}

// One-time: D [M][N] fp32 -> Dperm hi/lo  (gemm2 B: r=m, k=n, K=2048)
//                        and Dtperm hi/lo (gemm1 B: r=n, k=m, K=512)
__global__ __launch_bounds__(256) void convD_kernel(const float* __restrict__ D,
        _Float16* __restrict__ Dph, _Float16* __restrict__ Dpl,
        _Float16* __restrict__ Dtph, _Float16* __restrict__ Dtpl) {
    __shared__ float T[64][65];
    const int t = threadIdx.x;
    const int tx = t & 15, ty = t >> 4;
    const int n0 = blockIdx.x << 6, m0 = blockIdx.y << 6;
#pragma unroll
    for (int q = 0; q < 4; ++q) {
        const int mr = m0 + (ty << 2) + q;
        const int nc = n0 + (tx << 2);
        float4 d = *(const float4*)(D + (size_t)mr * Nsz + nc);
        half4 h, l;
        HL s0 = split1(d.x), s1 = split1(d.y), s2 = split1(d.z), s3 = split1(d.w);
        h[0] = s0.h; l[0] = s0.l; h[1] = s1.h; l[1] = s1.l;
        h[2] = s2.h; l[2] = s2.l; h[3] = s3.h; l[3] = s3.l;
        const size_t o2 = ((size_t)(mr >> 5) * 128 + (nc >> 4)) * 512
                        + ((mr & 31) << 4) + (nc & 15);
        *(half4*)(Dph + o2) = h;
        *(half4*)(Dpl + o2) = l;
        T[(tx << 2) + 0][(ty << 2) + q] = d.x;
        T[(tx << 2) + 1][(ty << 2) + q] = d.y;
        T[(tx << 2) + 2][(ty << 2) + q] = d.z;
        T[(tx << 2) + 3][(ty << 2) + q] = d.w;
    }
    __syncthreads();
#pragma unroll
    for (int q = 0; q < 4; ++q) {
        const int nr = n0 + (ty << 2) + q;
        const int mc = m0 + (tx << 2);
        float4 d = make_float4(T[(ty << 2) + q][tx << 2],
                               T[(ty << 2) + q][(tx << 2) + 1],
                               T[(ty << 2) + q][(tx << 2) + 2],
                               T[(ty << 2) + q][(tx << 2) + 3]);
        half4 h, l;
        HL s0 = split1(d.x), s1 = split1(d.y), s2 = split1(d.z), s3 = split1(d.w);
        h[0] = s0.h; l[0] = s0.l; h[1] = s1.h; l[1] = s1.l;
        h[2] = s2.h; l[2] = s2.l; h[3] = s3.h; l[3] = s3.l;
        const size_t o1 = ((size_t)(nr >> 5) * 32 + (mc >> 4)) * 512
                        + ((nr & 31) << 4) + (mc & 15);
        *(half4*)(Dtph + o1) = h;
        *(half4*)(Dtpl + o1) = l;
    }
}

// gemm1: alpha = relu((first?0:alpha) + beta*(v@D) - t[b]); fused na2 atomic.
// 2-term split: A = v single f16 plane; B = Dt hi/lo. 3 planes via global_load_lds,
// 24KB LDS, fragment format. 128x128 block, 4 waves 2x2, 32x32x16 MFMA, K=512.
__global__ __launch_bounds__(256, 4) void gemm1_kernel(
        const _Float16* __restrict__ Av,
        const _Float16* __restrict__ Bth, const _Float16* __restrict__ Btl,
        const float* __restrict__ t2,
        uint* __restrict__ alphaP,
        float* __restrict__ na2,
        const float* __restrict__ beta_p, const float* __restrict__ gamma_p,
        int first, int last) {
    __shared__ _Float16 lds[12288];   // 24KB: A | Bh | Bl, 4096 halves each

    const int tid = threadIdx.x;
    const int wave = tid >> 6, lane = tid & 63;
    const int wy = wave >> 1, wx = wave & 1;
    const int ln = lane & 31, lh = lane >> 5;
    const int bid = blockIdx.x;
    const int b0 = (bid & 127) << 7;    // row-tile sharers (stride-128 bids) -> same XCD
    const int n0 = (bid >> 7) << 7;
    const int R0 = b0 >> 5, C0 = n0 >> 5;

    floatx16 acc[2][2] = {};

    // staging: wave0 -> A plane, wave1 -> Bh, wave2 -> Bl, wave3 idle
    const _Float16* gsrc =
        (wave == 0) ? Av + (size_t)R0 * 32 * 512 :
        (wave == 1) ? Bth + (size_t)C0 * 32 * 512 :
                      Btl + (size_t)C0 * 32 * 512;
    gsrc += lane * 8;                    // 16B per lane
    _Float16* lplane = lds + wave * 4096;

    const int ro = ln * 16 + lh * 8;     // in-fragment lane offset (halves)

    for (int c = 0; c < 16; ++c) {
        __syncthreads();                 // previous chunk's frag reads done
        if (wave < 3) {
#pragma unroll
            for (int f = 0; f < 8; ++f) {    // frag (rtile i = f>>1, ktile j = f&1)
                const int i = f >> 1, j = f & 1;
                gl_lds16(gsrc + (((size_t)i * 32 + 2 * c + j) << 9), lplane + (f << 9));
            }
        }
        __builtin_amdgcn_s_waitcnt(0);   // drain this wave's DMA
        __syncthreads();                 // all planes staged

#pragma unroll
        for (int ks = 0; ks < 2; ++ks) {
            half8 fa[2], fbh[2], fbl[2];
#pragma unroll
            for (int i = 0; i < 2; ++i) {
                const int sa = (((wy * 2 + i) << 1) + ks) << 9;
                const int sb = (((wx * 2 + i) << 1) + ks) << 9;
                fa[i]  = *(const half8*)(lds + sa + ro);
                fbh[i] = *(const half8*)(lds + 4096 + sb + ro);
                fbl[i] = *(const half8*)(lds + 8192 + sb + ro);
            }
#pragma unroll
            for (int j = 0; j < 2; ++j)
#pragma unroll
                for (int i = 0; i < 2; ++i) {
                    acc[i][j] = __builtin_amdgcn_mfma_f32_32x32x16_f16(fa[i], fbh[j], acc[i][j], 0, 0, 0);
                    acc[i][j] = __builtin_amdgcn_mfma_f32_32x32x16_f16(fa[i], fbl[j], acc[i][j], 0, 0, 0);
                }
        }
    }

    const float beta = beta_p[0];
    const float tc = gamma_p[0] * 0.044194173824159216f;   // gamma / sqrt(512)
#pragma unroll
    for (int i = 0; i < 2; ++i) {
#pragma unroll
        for (int reg = 0; reg < 16; ++reg) {
            const int rr = (reg & 3) + 8 * (reg >> 2) + 4 * lh;   // 0..31
            const int b = b0 + wy * 64 + i * 32 + rr;
            const float tb = tc * sqrtf(t2[b]);
            uint* arow = alphaP + (size_t)b * Nsz + n0 + wx * 64 + ln;
            float s = 0.f;
#pragma unroll
            for (int j = 0; j < 2; ++j) {
                float z = first ? 0.f : unpackHL(arow[j * 32]);
                float val = fmaxf(fmaf(beta, acc[i][j][reg], z) - tb, 0.f);
                if (last) ((float*)arow)[j * 32] = val;   // final fp32, same 4-B slot
                else      arow[j * 32] = packHL(val);
                s = fmaf(val, val, s);
            }
            s += __shfl_down(s, 16, 32);
            s += __shfl_down(s, 8, 32);
            s += __shfl_down(s, 4, 32);
            s += __shfl_down(s, 2, 32);
            s += __shfl_down(s, 1, 32);
            if (ln == 0) atomicAdd(&na2[b], s);
        }
    }
}

// gemm2: v = y - beta*(alpha@D^T) + beta/512*sqrt(na2[b])*v_old; fused t2 atomic.
// 2-term split: A = alpha_hi (extracted from packed, ds_write in frag format);
// B = D hi/lo via global_load_lds (waves 0/1). 128x128 block, K=2048 (64 chunks).
__global__ __launch_bounds__(256, 2) void gemm2_kernel(
        const uint* __restrict__ alphaP,
        const _Float16* __restrict__ Bh, const _Float16* __restrict__ Bl,
        const float* __restrict__ na2,
        const float* __restrict__ y,
        _Float16* __restrict__ vh,
        float* __restrict__ t2,
        const float* __restrict__ beta_p) {
    __shared__ _Float16 lds[12288];   // A | Bh | Bl, 4096 halves each

    const int tid = threadIdx.x;
    const int wave = tid >> 6, lane = tid & 63;
    const int wy = wave >> 1, wx = wave & 1;
    const int ln = lane & 31, lh = lane >> 5;
    const int bid = blockIdx.x;
    const int b0 = (bid & 127) << 7;
    const int m0 = (bid >> 7) << 7;
    const int C0 = m0 >> 5;

    floatx16 acc[2][2] = {};

    // A staging: thread (srow, skq) covers one ktile-half of one row (16 words)
    const int srow = tid >> 1;
    const int skq  = (tid & 1) << 4;
    const uint* apP = alphaP + (size_t)(b0 + srow) * Nsz + skq;
    _Float16* aw = lds + ((((srow >> 5) << 1) + (skq >> 4)) << 9) + ((srow & 31) << 4);

    // B staging via gl_lds: wave0 -> Bh plane, wave1 -> Bl plane
    const _Float16* gB = ((wave & 1) ? Bl : Bh) + (size_t)C0 * 128 * 512 + lane * 8;
    _Float16* lB = lds + 4096 + (wave & 1) * 4096;

    const int ro = ln * 16 + lh * 8;

    uint4 a0 = *(const uint4*)(apP);
    uint4 a1 = *(const uint4*)(apP + 4);
    uint4 a2 = *(const uint4*)(apP + 8);
    uint4 a3 = *(const uint4*)(apP + 12);

    for (int c = 0; c < 64; ++c) {
        // extract hi (low16s) of current A regs
        uint4 ha, hb;
        ha.x = __builtin_amdgcn_perm(a0.y, a0.x, 0x05040100u);
        ha.y = __builtin_amdgcn_perm(a0.w, a0.z, 0x05040100u);
        ha.z = __builtin_amdgcn_perm(a1.y, a1.x, 0x05040100u);
        ha.w = __builtin_amdgcn_perm(a1.w, a1.z, 0x05040100u);
        hb.x = __builtin_amdgcn_perm(a2.y, a2.x, 0x05040100u);
        hb.y = __builtin_amdgcn_perm(a2.w, a2.z, 0x05040100u);
        hb.z = __builtin_amdgcn_perm(a3.y, a3.x, 0x05040100u);
        hb.w = __builtin_amdgcn_perm(a3.w, a3.z, 0x05040100u);

        // prefetch next chunk's A (completes during barrier+MFMA span)
        if (c < 63) {
            const uint* nx = apP + (c + 1) * 32;
            a0 = *(const uint4*)(nx);
            a1 = *(const uint4*)(nx + 4);
            a2 = *(const uint4*)(nx + 8);
            a3 = *(const uint4*)(nx + 12);
        }

        __syncthreads();                 // previous chunk's frag reads done
        if (wave < 2) {
#pragma unroll
            for (int f = 0; f < 8; ++f) {
                const int i = f >> 1, j = f & 1;
                gl_lds16(gB + (((size_t)i * 128 + 2 * c + j) << 9), lB + (f << 9));
            }
        }
        *(uint4*)aw = ha; *(uint4*)(aw + 8) = hb;
        __builtin_amdgcn_s_waitcnt(0);
        __syncthreads();

#pragma unroll
        for (int ks = 0; ks < 2; ++ks) {
            half8 fa[2], fbh[2], fbl[2];
#pragma unroll
            for (int i = 0; i < 2; ++i) {
                const int sa = (((wy * 2 + i) << 1) + ks) << 9;
                const int sb = (((wx * 2 + i) << 1) + ks) << 9;
                fa[i]  = *(const half8*)(lds + sa + ro);
                fbh[i] = *(const half8*)(lds + 4096 + sb + ro);
                fbl[i] = *(const half8*)(lds + 8192 + sb + ro);
            }
#pragma unroll
            for (int j = 0; j < 2; ++j)
#pragma unroll
                for (int i = 0; i < 2; ++i) {
                    acc[i][j] = __builtin_amdgcn_mfma_f32_32x32x16_f16(fa[i], fbh[j], acc[i][j], 0, 0, 0);
                    acc[i][j] = __builtin_amdgcn_mfma_f32_32x32x16_f16(fa[i], fbl[j], acc[i][j], 0, 0, 0);
                }
        }
    }

    const float beta = beta_p[0];
#pragma unroll
    for (int i = 0; i < 2; ++i) {
#pragma unroll
        for (int reg = 0; reg < 16; ++reg) {
            const int rr = (reg & 3) + 8 * (reg >> 2) + 4 * lh;
            const int b = b0 + wy * 64 + i * 32 + rr;
            const float cb = beta * (1.0f / 512.0f) * sqrtf(na2[b]);
            float s = 0.f;
#pragma unroll
            for (int j = 0; j < 2; ++j) {
                const int m = m0 + wx * 64 + j * 32 + ln;
                const size_t po = ((size_t)(b >> 5) * 32 + (m >> 4)) * 512
                                + ((b & 31) << 4) + (m & 15);
                const size_t yi = (size_t)b * Msz + m;
                float vold = (float)vh[po];
                float val = y[yi] - beta * acc[i][j][reg] + cb * vold;
                vh[po] = (_Float16)val;
                s = fmaf(val, val, s);
            }
            s += __shfl_down(s, 16, 32);
            s += __shfl_down(s, 8, 32);
            s += __shfl_down(s, 4, 32);
            s += __shfl_down(s, 2, 32);
            s += __shfl_down(s, 1, 32);
            if (ln == 0) atomicAdd(&t2[b], s);
        }
    }
}

extern "C" void kernel_launch(void* const* d_in, const int* in_sizes, int n_in,
                              void* d_out, int out_size, void* d_ws, size_t ws_size,
                              hipStream_t stream) {
    (void)in_sizes; (void)n_in; (void)out_size; (void)ws_size;
    const float* batch   = (const float*)d_in[0];   // [B, M]
    const float* D       = (const float*)d_in[1];   // [M, N]
    const float* gamma_p = (const float*)d_in[2];   // scalar
    const float* beta_p  = (const float*)d_in[3];   // scalar

    uint* alphaP = (uint*)d_out;    // packed hi/lo per element (plain layout); fp32 after final iter

    // workspace (~27 MB)
    _Float16* vh   = (_Float16*)d_ws;               // [B*M] permuted, single plane
    _Float16* Dph  = vh + (size_t)Bsz * Msz;        // [M*N] permuted (gemm2 B)
    _Float16* Dpl  = Dph + (size_t)Msz * Nsz;
    _Float16* Dtph = Dpl + (size_t)Msz * Nsz;       // [N*M] permuted (gemm1 B)
    _Float16* Dtpl = Dtph + (size_t)Msz * Nsz;
    float*    t2s  = (float*)(Dtpl + (size_t)Msz * Nsz);   // [10][Bsz] sum v^2
    float*    na2s = t2s + 10 * Bsz;                        // [10][Bsz] sum alpha^2

    // zero t2 slabs 1..9 + na2 slabs 0..9 (contiguous 19*Bsz floats)
    zero_kernel<<<19 * Bsz / 1024, 256, 0, stream>>>((float4*)(t2s + Bsz));
    convD_kernel<<<dim3(Nsz / 64, Msz / 64), 256, 0, stream>>>(D, Dph, Dpl, Dtph, Dtpl);
    init_kernel<<<Bsz / 4, 256, 0, stream>>>(batch, vh, t2s);   // writes t2 slab 0

    for (int it = 0; it < 10; ++it) {
        gemm1_kernel<<<2048, 256, 0, stream>>>(vh, Dtph, Dtpl,
                                               t2s + (size_t)it * Bsz,
                                               alphaP,
                                               na2s + (size_t)it * Bsz,
                                               beta_p, gamma_p,
                                               it == 0 ? 1 : 0, it == 9 ? 1 : 0);
        if (it < 9) {   // last iteration's new_v is unused by the reference output
            gemm2_kernel<<<512, 256, 0, stream>>>(alphaP, Dph, Dpl,
                                                  na2s + (size_t)it * Bsz,
                                                  batch, vh,
                                                  t2s + (size_t)(it + 1) * Bsz,
                                                  beta_p);
        }
    }
}